// Round 13
// baseline (1721.684 us; speedup 1.0000x reference)
//
#include <hip/hip_runtime.h>
#include <hip/hip_cooperative_groups.h>
#include <math.h>

namespace cg = cooperative_groups;

#define GF_BIAS   1
#define GF_RELU   2
#define GF_RESID  4
#define GF_POSENC 8
#define GF_F32OUT 16
#define GF_SWAP   64

namespace {
constexpr int BB = 4, SS = 1024, DD = 224, FFF = 600, VV = 8000, LLl = 8;
constexpr int SD = SS * DD;  // 229376
constexpr float INV_SD = 1.0f / (float)SD;

// workspace layout, bf16 element offsets
constexpr size_t WP   = 0;                         // [256][768]
constexpr size_t WQKV = WP + (size_t)256 * 768;    // L x [704][256]
constexpr size_t WO   = WQKV + (size_t)LLl * 704 * 256;
constexpr size_t W1T  = WO + (size_t)LLl * 256 * 256;
constexpr size_t W2T  = W1T + (size_t)LLl * 640 * 256;
constexpr size_t W3T  = W2T + (size_t)LLl * 640 * 640;
constexpr size_t WFT  = W3T + (size_t)LLl * 256 * 640;   // [8064][256]
constexpr size_t HB   = WFT + (size_t)8064 * 256;        // X (pre-LN state)
constexpr size_t H2B  = HB + (size_t)4096 * 256;         // hF (logits input)
constexpr size_t OBUF = H2B + (size_t)4096 * 256;
constexpr size_t BIG  = OBUF + (size_t)4096 * 256;       // xb | qkv
constexpr size_t ENDB = BIG + (size_t)2 * 4096 * 640;
constexpr size_t FBYTE = ENDB * 2;                       // float region byte offset
}

using short8 = __attribute__((ext_vector_type(8))) short;
using f32x4  = __attribute__((ext_vector_type(4))) float;

__device__ __forceinline__ float bits2f(unsigned u) {
  union { unsigned u; float f; } v; v.u = u; return v.f;
}
__device__ __forceinline__ unsigned short f2b(float f) {
  union { float f; unsigned u; } v; v.f = f;
  unsigned r = v.u + 0x7FFFu + ((v.u >> 16) & 1u);
  return (unsigned short)(r >> 16);
}
__device__ __forceinline__ float b2f(unsigned short b) {
  return bits2f((unsigned)b << 16);
}

// LN-transform 8 bf16 elements (one 16B chunk) with per-element w,b.
__device__ __forceinline__ uint4 ln8(uint4 raw, const float* __restrict__ wp,
                                     const float* __restrict__ bp,
                                     float mu1, float rs1, float mu2, float rs2,
                                     bool dbl) {
  float4 w0 = *(const float4*)wp, w1v = *(const float4*)(wp + 4);
  float4 b0 = *(const float4*)bp, b1v = *(const float4*)(bp + 4);
  float wv[8] = {w0.x, w0.y, w0.z, w0.w, w1v.x, w1v.y, w1v.z, w1v.w};
  float bv[8] = {b0.x, b0.y, b0.z, b0.w, b1v.x, b1v.y, b1v.z, b1v.w};
  const unsigned* u = (const unsigned*)&raw;
  uint4 out;
  unsigned* ou = (unsigned*)&out;
#pragma unroll
  for (int q = 0; q < 4; ++q) {
    float x0 = bits2f(u[q] << 16), x1 = bits2f(u[q] & 0xFFFF0000u);
    float y0 = (x0 - mu1) * rs1 * wv[q * 2] + bv[q * 2];
    float y1 = (x1 - mu1) * rs1 * wv[q * 2 + 1] + bv[q * 2 + 1];
    if (dbl) {
      y0 = (y0 - mu2) * rs2 * wv[q * 2] + bv[q * 2];
      y1 = (y1 - mu2) * rs2 * wv[q * 2 + 1] + bv[q * 2 + 1];
    }
    ou[q] = (unsigned)f2b(y0) | ((unsigned)f2b(y1) << 16);
  }
  return out;
}

// double-LN stats from 6 sums + 5 layer constants
__device__ __forceinline__ void ln2stats(const float* __restrict__ st,
                                         const float* __restrict__ cst,
                                         float& mu1, float& rs1, float& mu2, float& rs2)
{
  mu1 = st[0] * INV_SD;
  rs1 = rsqrtf(st[1] * INV_SD - mu1 * mu1 + 1e-5f);
  mu2 = (rs1 * (st[2] - mu1 * cst[0]) + cst[2]) * INV_SD;
  const float ey2 = (rs1 * rs1 * (st[4] - 2.f * mu1 * st[3] + mu1 * mu1 * cst[1]) +
                     2.f * rs1 * (st[5] - mu1 * cst[4]) + cst[3]) * INV_SD;
  rs2 = rsqrtf(ey2 - mu2 * mu2 + 1e-5f);
}

// ---------------------------------------------------------------------------
// bf16 MFMA GEMM (plain paths only: proj / qkv0 / logits).
// ---------------------------------------------------------------------------
template <int BM, int BN, int FLAGS>
__global__ __launch_bounds__(256) void gemm_mfma(
    const unsigned short* __restrict__ A, const unsigned short* __restrict__ Bt,
    const float* __restrict__ bias, void* __restrict__ Cout, int Kp, int N, int ldc)
{
  constexpr int MR = BM / 32, NR = BN / 32;
  constexpr int APT = BM / 32, BPT = BN / 32;
  constexpr int ABY = BM * 128, BBY = BN * 128;   // bytes (BK=64)
  constexpr int CBY = (FLAGS & GF_F32OUT) ? (64 * (BN + 4) * 4) : (BM * (BN + 8) * 2);
  constexpr int SBY = (ABY + BBY) > CBY ? (ABY + BBY) : CBY;
  __shared__ __align__(16) char smem[SBY];
  unsigned short* sA = (unsigned short*)smem;
  unsigned short* sB = (unsigned short*)(smem + ABY);
  const int t = threadIdx.x;
  const int l = t & 63;
  const int w = t >> 6, wr = w >> 1, wc = w & 1;
  const int m0 = ((FLAGS & GF_SWAP) ? blockIdx.x : blockIdx.y) * BM;
  const int n0 = ((FLAGS & GF_SWAP) ? blockIdx.y : blockIdx.x) * BN;
  const int nk = Kp >> 6;

  int aoff[APT], ar[APT], ac[APT];
#pragma unroll
  for (int p = 0; p < APT; ++p) {
    int off = (t + p * 256) * 16;
    int r = off >> 7;
    int cb = (off & 127) ^ ((r & 7) << 4);
    aoff[p] = off; ar[p] = r; ac[p] = cb >> 1;
  }
  int boff[BPT], br[BPT], bc[BPT];
#pragma unroll
  for (int p = 0; p < BPT; ++p) {
    int off = (t + p * 256) * 16;
    int r = off >> 7;
    int cb = (off & 127) ^ ((r & 7) << 4);
    boff[p] = off; br[p] = r; bc[p] = cb >> 1;
  }

  const unsigned short* Ab = A + (size_t)m0 * Kp;
  const unsigned short* Bb = Bt + (size_t)n0 * Kp;

  uint4 ra[APT], rb[BPT];
#pragma unroll
  for (int p = 0; p < APT; ++p) ra[p] = *(const uint4*)(Ab + (size_t)ar[p] * Kp + ac[p]);
#pragma unroll
  for (int p = 0; p < BPT; ++p) rb[p] = *(const uint4*)(Bb + (size_t)br[p] * Kp + bc[p]);

  f32x4 acc[MR][NR];
#pragma unroll
  for (int i = 0; i < MR; ++i)
#pragma unroll
    for (int j = 0; j < NR; ++j) acc[i][j] = {0.f, 0.f, 0.f, 0.f};

  for (int kt = 0; kt < nk; ++kt) {
#pragma unroll
    for (int p = 0; p < APT; ++p) *(uint4*)((char*)sA + aoff[p]) = ra[p];
#pragma unroll
    for (int p = 0; p < BPT; ++p) *(uint4*)((char*)sB + boff[p]) = rb[p];
    __syncthreads();
    if (kt + 1 < nk) {
      const int k1 = (kt + 1) * 64;
#pragma unroll
      for (int p = 0; p < APT; ++p) ra[p] = *(const uint4*)(Ab + (size_t)ar[p] * Kp + k1 + ac[p]);
#pragma unroll
      for (int p = 0; p < BPT; ++p) rb[p] = *(const uint4*)(Bb + (size_t)br[p] * Kp + k1 + bc[p]);
    }
#pragma unroll
    for (int kh = 0; kh < 2; ++kh) {
      short8 af[MR], bfg[NR];
#pragma unroll
      for (int mi = 0; mi < MR; ++mi) {
        const int row = wr * (BM / 2) + mi * 16 + (l & 15);
        const int byte = (row * 128 + kh * 64 + (l >> 4) * 16) ^ ((row & 7) << 4);
        af[mi] = *(const short8*)((const char*)sA + byte);
      }
#pragma unroll
      for (int ni = 0; ni < NR; ++ni) {
        const int row = wc * (BN / 2) + ni * 16 + (l & 15);
        const int byte = (row * 128 + kh * 64 + (l >> 4) * 16) ^ ((row & 7) << 4);
        bfg[ni] = *(const short8*)((const char*)sB + byte);
      }
#pragma unroll
      for (int mi = 0; mi < MR; ++mi)
#pragma unroll
        for (int ni = 0; ni < NR; ++ni)
          acc[mi][ni] = __builtin_amdgcn_mfma_f32_16x16x32_bf16(af[mi], bfg[ni], acc[mi][ni], 0, 0, 0);
    }
    __syncthreads();
  }

  const int cl = l & 15, rl0 = (l >> 4) * 4;

  if constexpr ((FLAGS & GF_F32OUT) != 0) {
    constexpr int CST = BN + 4;
    float* Cs = (float*)smem;
    constexpr int NCH = BM / 64;
#pragma unroll
    for (int c = 0; c < NCH; ++c) {
      __syncthreads();
      if ((wr * (BM / 2)) / 64 == c) {
#pragma unroll
        for (int mi = 0; mi < MR; ++mi)
#pragma unroll
          for (int ni = 0; ni < NR; ++ni)
#pragma unroll
            for (int j = 0; j < 4; ++j) {
              const int rl = wr * (BM / 2) + mi * 16 + rl0 + j - c * 64;
              const int cc = wc * (BN / 2) + ni * 16 + cl;
              const int gn = n0 + cc;
              float v = acc[mi][ni][j];
              if ((FLAGS & GF_BIAS) && gn < N) v += bias[gn];
              Cs[rl * CST + cc] = v;
            }
      }
      __syncthreads();
      constexpr int CPR = BN / 4;
      constexpr int NIT = (64 * CPR) / 256;
#pragma unroll
      for (int i = 0; i < NIT; ++i) {
        const int ch = i * 256 + t;
        const int rr = ch / CPR, c4 = ch % CPR;
        const int gn = n0 + c4 * 4;
        const size_t gmr = (size_t)(m0 + c * 64 + rr);
        if (gn + 3 < N) {
          *(float4*)&((float*)Cout)[gmr * ldc + gn] = *(const float4*)&Cs[rr * CST + c4 * 4];
        } else {
#pragma unroll
          for (int c2 = 0; c2 < 4; ++c2)
            if (gn + c2 < N) ((float*)Cout)[gmr * ldc + gn + c2] = Cs[rr * CST + c4 * 4 + c2];
        }
      }
    }
  } else {
    constexpr int CST = BN + 8;
    unsigned short* Cs = (unsigned short*)smem;
#pragma unroll
    for (int mi = 0; mi < MR; ++mi)
#pragma unroll
      for (int ni = 0; ni < NR; ++ni)
#pragma unroll
        for (int j = 0; j < 4; ++j) {
          const int rl = wr * (BM / 2) + mi * 16 + rl0 + j;
          const int cc = wc * (BN / 2) + ni * 16 + cl;
          const int gm = m0 + rl, gn = n0 + cc;
          const int srow = gm & (SS - 1);
          float v = acc[mi][ni][j];
          if ((FLAGS & GF_BIAS) && gn < N) v += bias[gn];
          if ((FLAGS & GF_POSENC) && gn < N) {
            float freq = expf(-(2.0f * gn / 224.0f) * 9.210340371976184f);
            float ang = (float)srow * freq;
            v += (gn & 1) ? cosf(ang) : sinf(ang);
          }
          Cs[rl * CST + cc] = f2b(v);
        }
    __syncthreads();
#pragma unroll
    for (int it = 0; it < BM / 32; ++it) {
      const int rr = it * 32 + (t >> 3), qq = t & 7;
      const size_t gm = (size_t)(m0 + rr);
      *(uint4*)&((unsigned short*)Cout)[gm * ldc + n0 + qq * 8] =
          *(const uint4*)&Cs[rr * CST + qq * 8];
    }
  }
}

// ---------------------------------------------------------------------------
// Cooperative layer-tail: Wo-GEMM (+LNLN resid, stats->stA)  | grid.sync |
// FFN (h2a LDS-resident, stats->stB, X out)  | grid.sync |  qkv_{l+1}.
// 256 blocks x 512 threads, 1 block/CU (co-resident).
// ---------------------------------------------------------------------------
__global__ __launch_bounds__(512) void layer_tail(
    const unsigned short* __restrict__ obuf, unsigned short* __restrict__ X,
    unsigned short* __restrict__ qkvb,
    const unsigned short* __restrict__ woT, const float* __restrict__ bo,
    const unsigned short* __restrict__ W1t, const unsigned short* __restrict__ W2t,
    const unsigned short* __restrict__ W3t,
    const float* __restrict__ b1, const float* __restrict__ b2,
    const float* __restrict__ b3,
    const unsigned short* __restrict__ wqN, const float* __restrict__ bcN,
    const float* __restrict__ lnwP, const float* __restrict__ lnbP,
    const float* __restrict__ cstP, const float* __restrict__ stPrev,
    const float* __restrict__ lnwL, const float* __restrict__ lnbL,
    const float* __restrict__ cstL,
    float* __restrict__ stA, float* __restrict__ stB,
    int isL0, int hasQkv)
{
  cg::grid_group grid = cg::this_grid();
  __shared__ __align__(16) char smem[59584];
  unsigned short* oS   = (unsigned short*)smem;              // 16x280 (phase W)
  unsigned short* sAx  = (unsigned short*)smem;              // alias (phase F/Q)
  unsigned short* h2aL = (unsigned short*)(smem + 8960);     // 16x280
  unsigned short* f1s  = (unsigned short*)(smem + 17920);    // 16x648
  unsigned short* f2s  = (unsigned short*)(smem + 38656);    // 16x648
  unsigned short* qS   = (unsigned short*)(smem + 17920);    // 16x712 (reuse)
  float* red6 = (float*)(smem + 59392);                      // 48 floats

  const int t = threadIdx.x;
  const int l = t & 63, w = t >> 6;          // w in [0,8)
  const int cl = l & 15, g8 = (l >> 4) * 8, rl0 = (l >> 4) * 4;
  const int m0 = blockIdx.x * 16;
  const int batch = m0 >> 10;

  // ---------------- phase W: h2a = obuf @ Wo + bo + LNLN(X) ----------------
  float mu1 = 0.f, rs1 = 1.f, mu2 = 0.f, rs2 = 1.f;
  if (!isL0) ln2stats(stPrev + batch * 6, cstP, mu1, rs1, mu2, rs2);

  {
    const int r = t >> 5, col = (t & 31) * 8;
    *(uint4*)(oS + r * 280 + col) = *(const uint4*)(obuf + (size_t)(m0 + r) * 256 + col);
  }
  __syncthreads();

  {
    f32x4 acc[2];
#pragma unroll
    for (int i = 0; i < 2; ++i) acc[i] = {0.f, 0.f, 0.f, 0.f};
    for (int ks = 0; ks < 8; ++ks) {
      const short8 af = *(const short8*)(oS + cl * 280 + ks * 32 + g8);
#pragma unroll
      for (int ni = 0; ni < 2; ++ni) {
        const int n = w * 32 + ni * 16 + cl;
        const short8 bf = *(const short8*)(woT + (size_t)n * 256 + ks * 32 + g8);
        acc[ni] = __builtin_amdgcn_mfma_f32_16x16x32_bf16(af, bf, acc[ni], 0, 0, 0);
      }
    }
    float s6[6] = {0.f, 0.f, 0.f, 0.f, 0.f, 0.f};
#pragma unroll
    for (int ni = 0; ni < 2; ++ni) {
      const int col = w * 32 + ni * 16 + cl;
#pragma unroll
      for (int j = 0; j < 4; ++j) {
        const int gm = m0 + rl0 + j;
        const int srow = gm & (SS - 1);
        float v = acc[ni][j];
        if (col < DD) {
          v += bo[col];
          float rv = b2f(X[(size_t)gm * 256 + col]);
          if (!isL0) {
            const float wE = lnwP[(size_t)srow * DD + col];
            const float bE = lnbP[(size_t)srow * DD + col];
            rv = (rv - mu1) * rs1 * wE + bE;
            rv = (rv - mu2) * rs2 * wE + bE;
          }
          v += rv;
          const float wS = lnwL[(size_t)srow * DD + col];
          const float bS = lnbL[(size_t)srow * DD + col];
          const float wv = wS * v;
          s6[0] += v; s6[1] += v * v; s6[2] += wv; s6[3] += wS * wv;
          s6[4] += wv * wv; s6[5] += bS * wv;
        }
        h2aL[(rl0 + j) * 280 + col] = f2b(v);
      }
    }
#pragma unroll
    for (int o2 = 32; o2 > 0; o2 >>= 1)
#pragma unroll
      for (int j2 = 0; j2 < 6; ++j2) s6[j2] += __shfl_down(s6[j2], o2);
    if (l == 0)
#pragma unroll
      for (int j2 = 0; j2 < 6; ++j2) red6[w * 6 + j2] = s6[j2];
    __syncthreads();
    if (t < 6) {
      float tot = 0.f;
#pragma unroll
      for (int ww = 0; ww < 8; ++ww) tot += red6[ww * 6 + t];
      atomicAdd(&stA[batch * 6 + t], tot);
    }
  }

  grid.sync();

  // ---------------- phase F: FFN ----------------
  {
    const float* sa = stA + batch * 6;
    const float muF = sa[0] * INV_SD;
    const float rsF = rsqrtf(sa[1] * INV_SD - muF * muF + 1e-5f);

    // stage sAx = LN(h2aL)
    {
      const int r = t >> 5, col = (t & 31) * 8;
      uint4 v = make_uint4(0u, 0u, 0u, 0u);
      if (col < DD) {
        const int srow = (m0 + r) & (SS - 1);
        uint4 raw = *(const uint4*)(h2aL + r * 280 + col);
        v = ln8(raw, lnwL + (size_t)srow * DD + col, lnbL + (size_t)srow * DD + col,
                muF, rsF, 0.f, 1.f, false);
      }
      *(uint4*)(sAx + r * 280 + col) = v;
    }
    __syncthreads();

    // f1 = relu(sAx @ W1^T + b1), wave n-slice 80
    {
      f32x4 acc[5];
#pragma unroll
      for (int i = 0; i < 5; ++i) acc[i] = {0.f, 0.f, 0.f, 0.f};
      for (int ks = 0; ks < 8; ++ks) {
        const short8 af = *(const short8*)(sAx + cl * 280 + ks * 32 + g8);
#pragma unroll
        for (int ni = 0; ni < 5; ++ni) {
          const int n = w * 80 + ni * 16 + cl;
          const short8 bf = *(const short8*)(W1t + (size_t)n * 256 + ks * 32 + g8);
          acc[ni] = __builtin_amdgcn_mfma_f32_16x16x32_bf16(af, bf, acc[ni], 0, 0, 0);
        }
      }
#pragma unroll
      for (int ni = 0; ni < 5; ++ni) {
        const int col = w * 80 + ni * 16 + cl;
        const float bias = (col < FFF) ? b1[col] : 0.f;
#pragma unroll
        for (int j = 0; j < 4; ++j)
          f1s[(rl0 + j) * 648 + col] = f2b(fmaxf(acc[ni][j] + bias, 0.f));
      }
    }
    __syncthreads();

    // f2 = relu(f1 @ W2^T + b2)
    {
      f32x4 acc[5];
#pragma unroll
      for (int i = 0; i < 5; ++i) acc[i] = {0.f, 0.f, 0.f, 0.f};
      for (int ks = 0; ks < 20; ++ks) {
        const short8 af = *(const short8*)(f1s + cl * 648 + ks * 32 + g8);
#pragma unroll
        for (int ni = 0; ni < 5; ++ni) {
          const int n = w * 80 + ni * 16 + cl;
          const short8 bf = *(const short8*)(W2t + (size_t)n * 640 + ks * 32 + g8);
          acc[ni] = __builtin_amdgcn_mfma_f32_16x16x32_bf16(af, bf, acc[ni], 0, 0, 0);
        }
      }
#pragma unroll
      for (int ni = 0; ni < 5; ++ni) {
        const int col = w * 80 + ni * 16 + cl;
        const float bias = (col < FFF) ? b2[col] : 0.f;
#pragma unroll
        for (int j = 0; j < 4; ++j)
          f2s[(rl0 + j) * 648 + col] = f2b(fmaxf(acc[ni][j] + bias, 0.f));
      }
    }
    __syncthreads();

    // X = f2 @ W3^T + b3 + LN(h2aL); stats -> stB; Cs = sAx
    float s6[6] = {0.f, 0.f, 0.f, 0.f, 0.f, 0.f};
    {
      f32x4 acc[2];
#pragma unroll
      for (int i = 0; i < 2; ++i) acc[i] = {0.f, 0.f, 0.f, 0.f};
      for (int ks = 0; ks < 20; ++ks) {
        const short8 af = *(const short8*)(f2s + cl * 648 + ks * 32 + g8);
#pragma unroll
        for (int ni = 0; ni < 2; ++ni) {
          const int n = w * 32 + ni * 16 + cl;
          const short8 bf = *(const short8*)(W3t + (size_t)n * 640 + ks * 32 + g8);
          acc[ni] = __builtin_amdgcn_mfma_f32_16x16x32_bf16(af, bf, acc[ni], 0, 0, 0);
        }
      }
#pragma unroll
      for (int ni = 0; ni < 2; ++ni) {
        const int col = w * 32 + ni * 16 + cl;
        const float bias = (col < DD) ? b3[col] : 0.f;
#pragma unroll
        for (int j = 0; j < 4; ++j) {
          const int gm = m0 + rl0 + j;
          const int srow = gm & (SS - 1);
          float v = acc[ni][j] + bias;
          if (col < DD) {
            const float wE = lnwL[(size_t)srow * DD + col];
            const float bE = lnbL[(size_t)srow * DD + col];
            v += (b2f(h2aL[(rl0 + j) * 280 + col]) - muF) * rsF * wE + bE;
            const float wv = wE * v;
            s6[0] += v; s6[1] += v * v; s6[2] += wv; s6[3] += wE * wv;
            s6[4] += wv * wv; s6[5] += bE * wv;
          }
          sAx[(rl0 + j) * 280 + col] = f2b(v);
        }
      }
    }
#pragma unroll
    for (int o2 = 32; o2 > 0; o2 >>= 1)
#pragma unroll
      for (int j2 = 0; j2 < 6; ++j2) s6[j2] += __shfl_down(s6[j2], o2);
    if (l == 0)
#pragma unroll
      for (int j2 = 0; j2 < 6; ++j2) red6[w * 6 + j2] = s6[j2];
    __syncthreads();
    if (t < 6) {
      float tot = 0.f;
#pragma unroll
      for (int ww = 0; ww < 8; ++ww) tot += red6[ww * 6 + t];
      atomicAdd(&stB[batch * 6 + t], tot);
    }
    // X global write (rows in sAx)
    {
      const int r = t >> 5, col = (t & 31) * 8;
      *(uint4*)(X + (size_t)(m0 + r) * 256 + col) = *(const uint4*)(sAx + r * 280 + col);
    }
  }

  if (!hasQkv) return;
  grid.sync();

  // ---------------- phase Q: qkv_{l+1} = LNLN(X) @ Wqkv + bq ----------------
  {
    float m1, r1, m2, r2;
    ln2stats(stB + batch * 6, cstL, m1, r1, m2, r2);
    short8 af2[8];
    const int srowA = (m0 + cl) & (SS - 1);
#pragma unroll
    for (int ks = 0; ks < 8; ++ks) {
      const int d0 = ks * 32 + g8;
      uint4 tr = make_uint4(0u, 0u, 0u, 0u);
      if (d0 < DD) {
        uint4 raw = *(const uint4*)(sAx + cl * 280 + d0);
        tr = ln8(raw, lnwL + (size_t)srowA * DD + d0, lnbL + (size_t)srowA * DD + d0,
                 m1, r1, m2, r2, true);
      }
      af2[ks] = *(const short8*)&tr;
    }
    __syncthreads();   // sAx reads done before qS (aliases fbuf) writes? qS != sAx; guards f2s reuse
    for (int idx = w; idx < 44; idx += 8) {
      f32x4 acc = {0.f, 0.f, 0.f, 0.f};
      const int nbase = idx * 16;
#pragma unroll
      for (int ks = 0; ks < 8; ++ks) {
        const short8 bf = *(const short8*)(wqN + (size_t)(nbase + cl) * 256 + ks * 32 + g8);
        acc = __builtin_amdgcn_mfma_f32_16x16x32_bf16(af2[ks], bf, acc, 0, 0, 0);
      }
      const int col = nbase + cl;
      const float bb = (col < 672) ? bcN[col] : 0.f;
#pragma unroll
      for (int j = 0; j < 4; ++j)
        qS[(rl0 + j) * 712 + col] = f2b(acc[j] + bb);
    }
    __syncthreads();
    for (int c = t; c < 1408; c += 512) {
      const int r = c / 88, q8 = (c % 88) * 8;
      *(uint4*)(qkvb + (size_t)(m0 + r) * 704 + q8) = *(const uint4*)(qS + r * 712 + q8);
    }
  }
}

// ---------------------------------------------------------------------------
// Materialize hF = LN(LN(X)) for the logits GEMM (analytic LN2 stats).
// ---------------------------------------------------------------------------
__global__ __launch_bounds__(256) void ln2mat(
    const unsigned short* __restrict__ X, const float* __restrict__ lnw,
    const float* __restrict__ lnb, const float* __restrict__ st,
    const float* __restrict__ cst, unsigned short* __restrict__ Y)
{
  const int chunk = blockIdx.x * 256 + threadIdx.x;   // 131072 = 4096*32
  const int r = chunk >> 5, cc = chunk & 31;
  if (cc >= 28) {
    *(uint4*)(Y + (size_t)r * 256 + cc * 8) = make_uint4(0u, 0u, 0u, 0u);
    return;
  }
  const int b = r >> 10, srow = r & 1023;
  float mu1, rs1, mu2, rs2;
  ln2stats(st + b * 6, cst, mu1, rs1, mu2, rs2);
  uint4 raw = *(const uint4*)(X + (size_t)r * 256 + cc * 8);
  uint4 out = ln8(raw, lnw + (size_t)srow * DD + cc * 8, lnb + (size_t)srow * DD + cc * 8,
                  mu1, rs1, mu2, rs2, true);
  *(uint4*)(Y + (size_t)r * 256 + cc * 8) = out;
}

// ---------------------------------------------------------------------------
// Unified weight prep (6 tensors + lnconst) in one flat-grid dispatch.
// ---------------------------------------------------------------------------
__device__ __forceinline__ void prep_wt2_body(
    const float* __restrict__ W, unsigned short* __restrict__ O,
    int K, int N, int Kp, int Np, size_t sW, size_t sO, int tile, int ll,
    float* __restrict__ T /* [32][36] */)
{
  const int tx = Np >> 5;
  const int tn = tile % tx, tk = tile / tx;
  const int n0 = tn * 32, k0 = tk * 32;
  const float* Wl = W + sW * ll;
  unsigned short* Ol = O + sO * ll;
  {
    const int r = threadIdx.x >> 3, c4 = (threadIdx.x & 7) * 4;
    const int k = k0 + r, n = n0 + c4;
    float4 v = make_float4(0.f, 0.f, 0.f, 0.f);
    if (k < K) {
      if (n + 3 < N) v = *(const float4*)&Wl[(size_t)k * N + n];
      else {
        if (n + 0 < N) v.x = Wl[(size_t)k * N + n + 0];
        if (n + 1 < N) v.y = Wl[(size_t)k * N + n + 1];
        if (n + 2 < N) v.z = Wl[(size_t)k * N + n + 2];
        if (n + 3 < N) v.w = Wl[(size_t)k * N + n + 3];
      }
    }
    *(float4*)&T[r * 36 + c4] = v;
  }
  __syncthreads();
  {
    const int nl = threadIdx.x >> 3, k4 = (threadIdx.x & 7) * 4;
    ushort4 u;
    u.x = f2b(T[(k4 + 0) * 36 + nl]); u.y = f2b(T[(k4 + 1) * 36 + nl]);
    u.z = f2b(T[(k4 + 2) * 36 + nl]); u.w = f2b(T[(k4 + 3) * 36 + nl]);
    *(ushort4*)&Ol[(size_t)(n0 + nl) * Kp + k0 + k4] = u;
  }
}

__global__ __launch_bounds__(256) void prep_weights(
    const float* __restrict__ Wp, const float* __restrict__ Wo,
    const float* __restrict__ W1, const float* __restrict__ W2,
    const float* __restrict__ W3, const float* __restrict__ Wf,
    const float* __restrict__ lnw, const float* __restrict__ lnb,
    unsigned short* __restrict__ wpT, unsigned short* __restrict__ woT,
    unsigned short* __restrict__ w1T, unsigned short* __restrict__ w2T,
    unsigned short* __restrict__ w3T, unsigned short* __restrict__ wfT,
    float* __restrict__ cst)
{
  __shared__ float T[32 * 36];
  const int b = blockIdx.x;
  if (b < 192) {
    prep_wt2_body(Wp, wpT, 768, 224, 768, 256, 0, 0, b, 0, T);
  } else if (b < 704) {
    const int f = b - 192;
    prep_wt2_body(Wo, woT, 224, 224, 256, 256, (size_t)224 * 224, (size_t)256 * 256,
                  f % 64, f / 64, T);
  } else if (b < 1984) {
    const int f = b - 704;
    prep_wt2_body(W1, w1T, 224, 600, 256, 640, (size_t)224 * 600, (size_t)640 * 256,
                  f % 160, f / 160, T);
  } else if (b < 5184) {
    const int f = b - 1984;
    prep_wt2_body(W2, w2T, 600, 600, 640, 640, (size_t)600 * 600, (size_t)640 * 640,
                  f % 400, f / 400, T);
  } else if (b < 6464) {
    const int f = b - 5184;
    prep_wt2_body(W3, w3T, 600, 224, 640, 256, (size_t)600 * 224, (size_t)256 * 640,
                  f % 160, f / 160, T);
  } else if (b < 8480) {
    prep_wt2_body(Wf, wfT, 224, 8000, 256, 8064, 0, 0, b - 6464, 0, T);
  } else {
    // lnconst: per-layer Sw, Sw2, Sb, Sb2, Swb
    const int f = b - 8480;             // 512 blocks: g in [0,64), ll in [0,8)
    const int g = f & 63, ll = f >> 6;
    const float* wv = lnw + (size_t)ll * SD + g * 3584;
    const float* bv = lnb + (size_t)ll * SD + g * 3584;
    float s[5] = {0.f, 0.f, 0.f, 0.f, 0.f};
    for (int c = threadIdx.x * 4; c < 3584; c += 1024) {
      float4 w4 = *(const float4*)(wv + c);
      float4 b4 = *(const float4*)(bv + c);
      const float* wf2 = (const float*)&w4;
      const float* bf2 = (const float*)&b4;
#pragma unroll
      for (int e = 0; e < 4; ++e) {
        const float ww = wf2[e], bb = bf2[e];
        s[0] += ww; s[1] += ww * ww; s[2] += bb; s[3] += bb * bb; s[4] += ww * bb;
      }
    }
#pragma unroll
    for (int o2 = 32; o2 > 0; o2 >>= 1)
#pragma unroll
      for (int j = 0; j < 5; ++j) s[j] += __shfl_down(s[j], o2);
    float* red = T;   // reuse
    if ((threadIdx.x & 63) == 0)
#pragma unroll
      for (int j = 0; j < 5; ++j) red[(threadIdx.x >> 6) * 5 + j] = s[j];
    __syncthreads();
    if (threadIdx.x < 5) {
      const float tot = red[threadIdx.x] + red[5 + threadIdx.x] +
                        red[10 + threadIdx.x] + red[15 + threadIdx.x];
      atomicAdd(&cst[ll * 5 + threadIdx.x], tot);
    }
  }
}

// Coalesced-read qkv weight repack (dest pre-zeroed so pads stay 0).
__global__ void prep_wqkv(const float* __restrict__ Wq, const float* __restrict__ Wk,
                          const float* __restrict__ Wv, const float* __restrict__ bq,
                          const float* __restrict__ bk, const float* __restrict__ bv,
                          unsigned short* __restrict__ O, float* __restrict__ bcat)
{
  const int idx = blockIdx.x * 256 + threadIdx.x;
  if (idx < LLl * 8 * 224 * 28) {
    const int kk = idx % 28;
    const int d  = (idx / 28) % 224;
    const int h  = (idx / (28 * 224)) % 8;
    const int ll = idx / (28 * 224 * 8);
    const int col = h * 28 + kk;
    const size_t base = (size_t)ll * (704 * 256);
    O[base + (size_t)col * 256 + d]         = f2b(Wq[idx]);
    O[base + (size_t)(224 + col) * 256 + d] = f2b(Wk[idx]);
    O[base + (size_t)(448 + col) * 256 + d] = f2b(Wv[idx]);
  }
  if (idx < LLl * 8 * 28) {
    const int kk = idx % 28;
    const int h  = (idx / 28) % 8;
    const int ll = idx / (28 * 8);
    const int col = h * 28 + kk;
    bcat[ll * 672 + col]       = bq[idx];
    bcat[ll * 672 + 224 + col] = bk[idx];
    bcat[ll * 672 + 448 + col] = bv[idx];
  }
}

// x -> bf16; block 0 zeros the stats/cst region (424 floats, STRIDED — the
// region exceeds blockDim; a plain guard left atomic accumulators dirty
// across graph replays: round-10 failure).
__global__ void prep_x(const float* __restrict__ x, unsigned short* __restrict__ xb,
                       float* __restrict__ st)
{
  if (blockIdx.x == 0) {
    for (int i = threadIdx.x; i < 424; i += 256) st[i] = 0.f;
  }
  const size_t i = ((size_t)blockIdx.x * 256 + threadIdx.x) * 4;
  float4 v = *(const float4*)(x + i);
  ushort4 o;
  o.x = f2b(v.x); o.y = f2b(v.y); o.z = f2b(v.z); o.w = f2b(v.w);
  *(ushort4*)(xb + i) = o;
}

// ---------------------------------------------------------------------------
// MFMA flash attention, defer-max rescale (identity-skip, bit-exact).
// ---------------------------------------------------------------------------
__global__ __launch_bounds__(256) void attn_mfma(const unsigned short* __restrict__ qkv,
                                                 unsigned short* __restrict__ o)
{
  const int bh = blockIdx.x;
  const int qt = (int)gridDim.y - 1 - (int)blockIdx.y;
  const int b = bh >> 3, h = bh & 7;
  const int tid = threadIdx.x;
  const int w = tid >> 6, l = tid & 63;
  const int cl = l & 15, g = l >> 4;
  const int qbase = qt * 64 + w * 16;
  const float scale = 0.1889822365046136f;  // 1/sqrt(28)

  __shared__ unsigned short Ks[32 * 40];
  __shared__ unsigned short Vt[32 * 40];
  __shared__ unsigned short Ps[4][16 * 40];

  short8 aq;
  {
    const unsigned short* qp = qkv + ((size_t)(b * SS + qbase + cl)) * 704 + h * 28;
#pragma unroll
    for (int e = 0; e < 8; ++e) {
      const int d = g * 8 + e;
      ((unsigned short*)&aq)[e] = (d < 28) ? qp[d] : (unsigned short)0;
    }
  }

  f32x4 o0 = {0.f, 0.f, 0.f, 0.f}, o1 = {0.f, 0.f, 0.f, 0.f};
  float m[4] = {-INFINITY, -INFINITY, -INFINITY, -INFINITY};
  float lsum[4] = {0.f, 0.f, 0.f, 0.f};

  const int ntiles = qt * 2 + 2;
  const int ntw = ((qbase + 15) >> 5) + 1;

  const int sr = tid >> 3, sc4 = (tid & 7) << 2;
  const bool sact = (sc4 < 28);
  ushort4 ku = make_ushort4(0, 0, 0, 0), vu = make_ushort4(0, 0, 0, 0);
  if (sact) {
    const unsigned short* kp = qkv + ((size_t)(b * SS + sr)) * 704 + 224 + h * 28 + sc4;
    ku = *(const ushort4*)kp;
    vu = *(const ushort4*)(kp + 224);
  }

  for (int tile = 0; tile < ntiles; ++tile) {
    const int t0 = tile * 32;
    __syncthreads();
    *(ushort4*)&Ks[sr * 40 + sc4] = ku;
    Vt[(sc4 + 0) * 40 + sr] = vu.x;
    Vt[(sc4 + 1) * 40 + sr] = vu.y;
    Vt[(sc4 + 2) * 40 + sr] = vu.z;
    Vt[(sc4 + 3) * 40 + sr] = vu.w;
    __syncthreads();
    if (tile + 1 < ntiles && sact) {
      const unsigned short* kp =
          qkv + ((size_t)(b * SS + (tile + 1) * 32 + sr)) * 704 + 224 + h * 28 + sc4;
      ku = *(const ushort4*)kp;
      vu = *(const ushort4*)(kp + 224);
    }
    if (tile >= ntw) continue;

    const short8 bk0 = *(const short8*)&Ks[cl * 40 + g * 8];
    const short8 bk1 = *(const short8*)&Ks[(cl + 16) * 40 + g * 8];
    f32x4 zz = {0.f, 0.f, 0.f, 0.f};
    f32x4 s0 = __builtin_amdgcn_mfma_f32_16x16x32_bf16(aq, bk0, zz, 0, 0, 0);
    f32x4 s1 = __builtin_amdgcn_mfma_f32_16x16x32_bf16(aq, bk1, zz, 0, 0, 0);

    const bool diag = (t0 + 31 > qbase);
#pragma unroll
    for (int jj = 0; jj < 4; ++jj) {
      float v0 = s0[jj] * scale, v1 = s1[jj] * scale;
      if (diag) {
        const int qr = qbase + g * 4 + jj;
        if (t0 + cl > qr)      v0 = -INFINITY;
        if (t0 + 16 + cl > qr) v1 = -INFINITY;
      }
      float rm = fmaxf(v0, v1);
      rm = fmaxf(rm, __shfl_xor(rm, 1));
      rm = fmaxf(rm, __shfl_xor(rm, 2));
      rm = fmaxf(rm, __shfl_xor(rm, 4));
      rm = fmaxf(rm, __shfl_xor(rm, 8));
      if (rm > m[jj]) {
        const float r2 = __expf(m[jj] - rm);   // first tile: exp(-inf)=0
        m[jj] = rm;
        lsum[jj] *= r2;
        o0[jj] *= r2; o1[jj] *= r2;
      }
      const float e0 = __expf(v0 - m[jj]), e1 = __expf(v1 - m[jj]);
      lsum[jj] += e0 + e1;
      Ps[w][(g * 4 + jj) * 40 + cl]      = f2b(e0);
      Ps[w][(g * 4 + jj) * 40 + cl + 16] = f2b(e1);
    }
    const short8 pa  = *(const short8*)&Ps[w][cl * 40 + g * 8];
    const short8 bv0 = *(const short8*)&Vt[cl * 40 + g * 8];
    const short8 bv1 = *(const short8*)&Vt[(cl + 16) * 40 + g * 8];
    o0 = __builtin_amdgcn_mfma_f32_16x16x32_bf16(pa, bv0, o0, 0, 0, 0);
    o1 = __builtin_amdgcn_mfma_f32_16x16x32_bf16(pa, bv1, o1, 0, 0, 0);
  }

#pragma unroll
  for (int jj = 0; jj < 4; ++jj) {
    float ls = lsum[jj];
    ls += __shfl_xor(ls, 1);
    ls += __shfl_xor(ls, 2);
    ls += __shfl_xor(ls, 4);
    ls += __shfl_xor(ls, 8);
    const float inv = 1.0f / ls;
    const int row = qbase + g * 4 + jj;
    unsigned short* op = o + ((size_t)(b * SS + row)) * 256 + h * 28;
    op[cl] = f2b(o0[jj] * inv);
    if (cl < 12) op[16 + cl] = f2b(o1[jj] * inv);
  }
}

// ---------------------------------------------------------------------------
// Row softmax over V=8000, in place on d_out (fp32), float4 path.
// ---------------------------------------------------------------------------
__global__ __launch_bounds__(256) void softmax_rows(float* __restrict__ logits)
{
  const int row = blockIdx.x;
  float* p = logits + (size_t)row * VV;
  __shared__ float4 buf[VV / 4];
  __shared__ float red[4];
  const int tid = threadIdx.x;

  float mx = -INFINITY;
  for (int i = tid; i < VV / 4; i += 256) {
    float4 v = *(const float4*)(p + i * 4);
    buf[i] = v;
    mx = fmaxf(fmaxf(fmaxf(mx, v.x), fmaxf(v.y, v.z)), v.w);
  }
#pragma unroll
  for (int o2 = 32; o2 > 0; o2 >>= 1) mx = fmaxf(mx, __shfl_down(mx, o2));
  if ((tid & 63) == 0) red[tid >> 6] = mx;
  __syncthreads();
  mx = fmaxf(fmaxf(red[0], red[1]), fmaxf(red[2], red[3]));
  __syncthreads();

  float s = 0.f;
  for (int i = tid; i < VV / 4; i += 256) {
    float4 v = buf[i];
    v.x = __expf(v.x - mx); v.y = __expf(v.y - mx);
    v.z = __expf(v.z - mx); v.w = __expf(v.w - mx);
    buf[i] = v;
    s += v.x + v.y + v.z + v.w;
  }
#pragma unroll
  for (int o2 = 32; o2 > 0; o2 >>= 1) s += __shfl_down(s, o2);
  if ((tid & 63) == 0) red[tid >> 6] = s;
  __syncthreads();
  s = red[0] + red[1] + red[2] + red[3];
  const float inv = 1.0f / s;
  for (int i = tid; i < VV / 4; i += 256) {
    float4 v = buf[i];
    v.x *= inv; v.y *= inv; v.z *= inv; v.w *= inv;
    *(float4*)(p + i * 4) = v;
  }
}

// ---------------------------------------------------------------------------
extern "C" void kernel_launch(void* const* d_in, const int* in_sizes, int n_in,
                              void* d_out, int out_size, void* d_ws, size_t ws_size,
                              hipStream_t stream) {
  const float* x   = (const float*)d_in[0];
  const float* Wp  = (const float*)d_in[1];
  const float* bp  = (const float*)d_in[2];
  const float* Wq  = (const float*)d_in[3];
  const float* bq  = (const float*)d_in[4];
  const float* Wk  = (const float*)d_in[5];
  const float* bk  = (const float*)d_in[6];
  const float* Wv  = (const float*)d_in[7];
  const float* bv  = (const float*)d_in[8];
  const float* Wo  = (const float*)d_in[9];
  const float* bo  = (const float*)d_in[10];
  const float* W1  = (const float*)d_in[11];
  const float* b1  = (const float*)d_in[12];
  const float* W2  = (const float*)d_in[13];
  const float* b2  = (const float*)d_in[14];
  const float* W3  = (const float*)d_in[15];
  const float* b3  = (const float*)d_in[16];
  const float* lnw = (const float*)d_in[17];
  const float* lnb = (const float*)d_in[18];
  const float* Wf  = (const float*)d_in[19];
  const float* bf  = (const float*)d_in[20];

  unsigned short* wsb = (unsigned short*)d_ws;
  unsigned short* wpT   = wsb + WP;
  unsigned short* wqkvT = wsb + WQKV;
  unsigned short* woT   = wsb + WO;
  unsigned short* w1T   = wsb + W1T;
  unsigned short* w2T   = wsb + W2T;
  unsigned short* w3T   = wsb + W3T;
  unsigned short* wfT   = wsb + WFT;
  unsigned short* X     = wsb + HB;    // pre-LN layer state
  unsigned short* hF    = wsb + H2B;   // logits input
  unsigned short* obuf  = wsb + OBUF;
  unsigned short* xb    = wsb + BIG;
  unsigned short* qkvb  = wsb + BIG;
  float* bcat  = (float*)((char*)d_ws + FBYTE);
  float* stats = bcat + LLl * 672;      // 16 slots x 24 floats = 384
  float* cstA  = stats + 384;           // 8 layers x 5 floats = 40

  // ---- prep ----
  hipMemsetAsync(wqkvT, 0, (size_t)LLl * 704 * 256 * 2, stream);
  prep_x<<<3072, 256, 0, stream>>>(x, xb, stats);   // block 0 zeros stats+cst (424)
  prep_wqkv<<<1568, 256, 0, stream>>>(Wq, Wk, Wv, bq, bk, bv, wqkvT, bcat);
  prep_weights<<<8992, 256, 0, stream>>>(Wp, Wo, W1, W2, W3, Wf, lnw, lnb,
                                         wpT, woT, w1T, w2T, w3T, wfT, cstA);

  // ---- proj + posenc: X = x @ Wp + bp + pe ----
  gemm_mfma<32, 64, GF_BIAS | GF_POSENC><<<dim3(4, 128), 256, 0, stream>>>(
      xb, wpT, bp, X, 768, 224, 256);
  // ---- qkv layer 0 (plain X) ----
  gemm_mfma<64, 64, GF_BIAS><<<dim3(11, 64), 256, 0, stream>>>(
      X, wqkvT, bcat, qkvb, 256, 672, 704);

  for (int l = 0; l < LLl; ++l) {
    attn_mfma<<<dim3(BB * 8, SS / 64), 256, 0, stream>>>(qkvb, obuf);

    const unsigned short* p_obuf = obuf;
    unsigned short* p_X = X;
    unsigned short* p_qkvb = qkvb;
    const unsigned short* p_woT = woT + (size_t)l * 256 * 256;
    const float* p_bo = bo + (size_t)l * 224;
    const unsigned short* p_w1T = w1T + (size_t)l * 640 * 256;
    const unsigned short* p_w2T = w2T + (size_t)l * 640 * 640;
    const unsigned short* p_w3T = w3T + (size_t)l * 256 * 640;
    const float* p_b1 = b1 + (size_t)l * 600;
    const float* p_b2 = b2 + (size_t)l * 600;
    const float* p_b3 = b3 + (size_t)l * 224;
    const int ln_ = (l + 1 < LLl) ? l + 1 : 0;
    const unsigned short* p_wq = wqkvT + (size_t)ln_ * 704 * 256;
    const float* p_bc = bcat + (size_t)ln_ * 672;
    const int lp = (l > 0) ? l - 1 : 0;
    const float* p_lnwP = lnw + (size_t)lp * SD;
    const float* p_lnbP = lnb + (size_t)lp * SD;
    const float* p_cstP = cstA + lp * 5;
    const float* p_stPrev = stats + (size_t)((l > 0) ? 2 * l - 1 : 0) * 24;
    const float* p_lnwL = lnw + (size_t)l * SD;
    const float* p_lnbL = lnb + (size_t)l * SD;
    const float* p_cstL = cstA + l * 5;
    float* p_stA = stats + (size_t)(2 * l) * 24;
    float* p_stB = stats + (size_t)(2 * l + 1) * 24;
    int isL0 = (l == 0) ? 1 : 0;
    int hasQkv = (l < LLl - 1) ? 1 : 0;

    void* args[] = {&p_obuf, &p_X, &p_qkvb, &p_woT, &p_bo,
                    &p_w1T, &p_w2T, &p_w3T, &p_b1, &p_b2, &p_b3,
                    &p_wq, &p_bc, &p_lnwP, &p_lnbP, &p_cstP, &p_stPrev,
                    &p_lnwL, &p_lnbL, &p_cstL, &p_stA, &p_stB, &isL0, &hasQkv};
    hipLaunchCooperativeKernel((void*)layer_tail, dim3(256), dim3(512),
                               args, 0, stream);
  }

  // ---- hF = LNLN(X; stB7), logits, softmax ----
  ln2mat<<<512, 256, 0, stream>>>(X, lnw + (size_t)7 * SD, lnb + (size_t)7 * SD,
                                  stats + (size_t)15 * 24, cstA + 7 * 5, hF);
  gemm_mfma<128, 128, GF_BIAS | GF_F32OUT | GF_SWAP><<<dim3(32, 63), 256, 0, stream>>>(
      hF, wfT, bf, (float*)d_out, 256, 8000, 8000);
  softmax_rows<<<4096, 256, 0, stream>>>((float*)d_out);
}

// Round 14
// 1248.789 us; speedup vs baseline: 1.3787x; 1.3787x over previous
//
#include <hip/hip_runtime.h>
#include <math.h>

#define GF_BIAS   1
#define GF_RELU   2
#define GF_RESID  4
#define GF_POSENC 8
#define GF_F32OUT 16
#define GF_STAT6  32
#define GF_SWAP   64
#define GF_LNA    128
#define GF_LNA2   256
#define GF_LNRES  512
#define GF_LNRES2 1024

namespace {
constexpr int BB = 4, SS = 1024, DD = 224, FFF = 600, VV = 8000, LLl = 8;
constexpr int SD = SS * DD;  // 229376
constexpr float INV_SD = 1.0f / (float)SD;

// workspace layout, bf16 element offsets
constexpr size_t WP   = 0;                         // [256][768]
constexpr size_t WQKV = WP + (size_t)256 * 768;    // L x [704][256]
constexpr size_t WO   = WQKV + (size_t)LLl * 704 * 256;
constexpr size_t W1T  = WO + (size_t)LLl * 256 * 256;
constexpr size_t W2T  = W1T + (size_t)LLl * 640 * 256;
constexpr size_t W3T  = W2T + (size_t)LLl * 640 * 640;
constexpr size_t WFT  = W3T + (size_t)LLl * 256 * 640;   // [8064][256]
constexpr size_t HB   = WFT + (size_t)8064 * 256;        // X (pre-LN state)
constexpr size_t H2B  = HB + (size_t)4096 * 256;         // h2a / hF
constexpr size_t OBUF = H2B + (size_t)4096 * 256;
constexpr size_t BIG  = OBUF + (size_t)4096 * 256;       // xb | qkv
constexpr size_t ENDB = BIG + (size_t)2 * 4096 * 640;
constexpr size_t FBYTE = ENDB * 2;                       // float region byte offset
}

using short8 = __attribute__((ext_vector_type(8))) short;
using f32x4  = __attribute__((ext_vector_type(4))) float;

__device__ __forceinline__ float bits2f(unsigned u) {
  union { unsigned u; float f; } v; v.u = u; return v.f;
}
__device__ __forceinline__ unsigned short f2b(float f) {
  union { float f; unsigned u; } v; v.f = f;
  unsigned r = v.u + 0x7FFFu + ((v.u >> 16) & 1u);
  return (unsigned short)(r >> 16);
}
__device__ __forceinline__ float b2f(unsigned short b) {
  return bits2f((unsigned)b << 16);
}

// LN-transform 8 bf16 elements (one 16B chunk) with per-element w,b.
__device__ __forceinline__ uint4 ln8(uint4 raw, const float* __restrict__ wp,
                                     const float* __restrict__ bp,
                                     float mu1, float rs1, float mu2, float rs2,
                                     bool dbl) {
  float4 w0 = *(const float4*)wp, w1v = *(const float4*)(wp + 4);
  float4 b0 = *(const float4*)bp, b1v = *(const float4*)(bp + 4);
  float wv[8] = {w0.x, w0.y, w0.z, w0.w, w1v.x, w1v.y, w1v.z, w1v.w};
  float bv[8] = {b0.x, b0.y, b0.z, b0.w, b1v.x, b1v.y, b1v.z, b1v.w};
  const unsigned* u = (const unsigned*)&raw;
  uint4 out;
  unsigned* ou = (unsigned*)&out;
#pragma unroll
  for (int q = 0; q < 4; ++q) {
    float x0 = bits2f(u[q] << 16), x1 = bits2f(u[q] & 0xFFFF0000u);
    float y0 = (x0 - mu1) * rs1 * wv[q * 2] + bv[q * 2];
    float y1 = (x1 - mu1) * rs1 * wv[q * 2 + 1] + bv[q * 2 + 1];
    if (dbl) {
      y0 = (y0 - mu2) * rs2 * wv[q * 2] + bv[q * 2];
      y1 = (y1 - mu2) * rs2 * wv[q * 2 + 1] + bv[q * 2 + 1];
    }
    ou[q] = (unsigned)f2b(y0) | ((unsigned)f2b(y1) << 16);
  }
  return out;
}

// ---------------------------------------------------------------------------
// bf16 MFMA GEMM with fused LN transforms and 6-sum stat epilogue.
// ---------------------------------------------------------------------------
template <int BM, int BN, int FLAGS>
__global__ __launch_bounds__(256) void gemm_mfma(
    const unsigned short* __restrict__ A, const unsigned short* __restrict__ Bt,
    const float* __restrict__ bias, const unsigned short* __restrict__ Rz,
    void* __restrict__ Cout, int Kp, int N, int ldc,
    const float* __restrict__ lnwT, const float* __restrict__ lnbT,
    const float* __restrict__ stIn, const float* __restrict__ cst,
    const float* __restrict__ lnwS, const float* __restrict__ lnbS,
    float* __restrict__ statOut)
{
  constexpr bool HASLNA = (FLAGS & (GF_LNA | GF_LNA2)) != 0;
  constexpr bool HASLNR = (FLAGS & (GF_LNRES | GF_LNRES2)) != 0;
  constexpr bool DBLA = (FLAGS & GF_LNA2) != 0;
  constexpr bool DBLR = (FLAGS & GF_LNRES2) != 0;
  constexpr int MR = BM / 32, NR = BN / 32;
  constexpr int APT = BM / 32, BPT = BN / 32;
  constexpr int ABY = BM * 128, BBY = BN * 128;   // bytes (BK=64)
  constexpr int CBY = (FLAGS & GF_F32OUT) ? (64 * (BN + 4) * 4) : (BM * (BN + 8) * 2);
  constexpr int SBY = (ABY + BBY) > CBY ? (ABY + BBY) : CBY;
  __shared__ __align__(16) char smem[SBY];
  __shared__ float red6[24];
  unsigned short* sA = (unsigned short*)smem;
  unsigned short* sB = (unsigned short*)(smem + ABY);
  const int t = threadIdx.x;
  const int l = t & 63;
  const int w = t >> 6, wr = w >> 1, wc = w & 1;
  const int m0 = ((FLAGS & GF_SWAP) ? blockIdx.x : blockIdx.y) * BM;
  const int n0 = ((FLAGS & GF_SWAP) ? blockIdx.y : blockIdx.x) * BN;
  const int nk = Kp >> 6;

  float mu1 = 0.f, rs1 = 1.f, mu2 = 0.f, rs2 = 1.f;
  if constexpr (HASLNA || HASLNR) {
    const float* st = stIn + (m0 >> 10) * 6;
    const float s0 = st[0], s1 = st[1];
    mu1 = s0 * INV_SD;
    rs1 = rsqrtf(s1 * INV_SD - mu1 * mu1 + 1e-5f);
    if constexpr (DBLA || DBLR) {
      const float swx = st[2], sw2x = st[3], sw2x2 = st[4], swbx = st[5];
      mu2 = (rs1 * (swx - mu1 * cst[0]) + cst[2]) * INV_SD;
      const float ey2 = (rs1 * rs1 * (sw2x2 - 2.f * mu1 * sw2x + mu1 * mu1 * cst[1]) +
                         2.f * rs1 * (swbx - mu1 * cst[4]) + cst[3]) * INV_SD;
      rs2 = rsqrtf(ey2 - mu2 * mu2 + 1e-5f);
    }
  }

  int aoff[APT], ar[APT], ac[APT];
#pragma unroll
  for (int p = 0; p < APT; ++p) {
    int off = (t + p * 256) * 16;
    int r = off >> 7;
    int cb = (off & 127) ^ ((r & 7) << 4);
    aoff[p] = off; ar[p] = r; ac[p] = cb >> 1;
  }
  int boff[BPT], br[BPT], bc[BPT];
#pragma unroll
  for (int p = 0; p < BPT; ++p) {
    int off = (t + p * 256) * 16;
    int r = off >> 7;
    int cb = (off & 127) ^ ((r & 7) << 4);
    boff[p] = off; br[p] = r; bc[p] = cb >> 1;
  }

  const unsigned short* Ab = A + (size_t)m0 * Kp;
  const unsigned short* Bb = Bt + (size_t)n0 * Kp;

  auto loadA = [&](int p, int kb) -> uint4 {
    const int d0 = kb + ac[p];
    uint4 raw = *(const uint4*)(Ab + (size_t)ar[p] * Kp + d0);
    if constexpr (HASLNA) {
      if (d0 >= DD) return make_uint4(0u, 0u, 0u, 0u);
      const int srow = (m0 + ar[p]) & (SS - 1);
      raw = ln8(raw, lnwT + (size_t)srow * DD + d0, lnbT + (size_t)srow * DD + d0,
                mu1, rs1, mu2, rs2, DBLA);
    }
    return raw;
  };

  uint4 ra[APT], rb[BPT];
#pragma unroll
  for (int p = 0; p < APT; ++p) ra[p] = loadA(p, 0);
#pragma unroll
  for (int p = 0; p < BPT; ++p) rb[p] = *(const uint4*)(Bb + (size_t)br[p] * Kp + bc[p]);

  f32x4 acc[MR][NR];
#pragma unroll
  for (int i = 0; i < MR; ++i)
#pragma unroll
    for (int j = 0; j < NR; ++j) acc[i][j] = {0.f, 0.f, 0.f, 0.f};

  for (int kt = 0; kt < nk; ++kt) {
#pragma unroll
    for (int p = 0; p < APT; ++p) *(uint4*)((char*)sA + aoff[p]) = ra[p];
#pragma unroll
    for (int p = 0; p < BPT; ++p) *(uint4*)((char*)sB + boff[p]) = rb[p];
    __syncthreads();
    if (kt + 1 < nk) {
      const int k1 = (kt + 1) * 64;
#pragma unroll
      for (int p = 0; p < APT; ++p) ra[p] = loadA(p, k1);
#pragma unroll
      for (int p = 0; p < BPT; ++p) rb[p] = *(const uint4*)(Bb + (size_t)br[p] * Kp + k1 + bc[p]);
    }
#pragma unroll
    for (int kh = 0; kh < 2; ++kh) {
      short8 af[MR], bfg[NR];
#pragma unroll
      for (int mi = 0; mi < MR; ++mi) {
        const int row = wr * (BM / 2) + mi * 16 + (l & 15);
        const int byte = (row * 128 + kh * 64 + (l >> 4) * 16) ^ ((row & 7) << 4);
        af[mi] = *(const short8*)((const char*)sA + byte);
      }
#pragma unroll
      for (int ni = 0; ni < NR; ++ni) {
        const int row = wc * (BN / 2) + ni * 16 + (l & 15);
        const int byte = (row * 128 + kh * 64 + (l >> 4) * 16) ^ ((row & 7) << 4);
        bfg[ni] = *(const short8*)((const char*)sB + byte);
      }
#pragma unroll
      for (int mi = 0; mi < MR; ++mi)
#pragma unroll
        for (int ni = 0; ni < NR; ++ni)
          acc[mi][ni] = __builtin_amdgcn_mfma_f32_16x16x32_bf16(af[mi], bfg[ni], acc[mi][ni], 0, 0, 0);
    }
    __syncthreads();
  }

  const int cl = l & 15, rl0 = (l >> 4) * 4;

  if constexpr ((FLAGS & GF_F32OUT) != 0) {
    constexpr int CST = BN + 4;
    float* Cs = (float*)smem;
    constexpr int NCH = BM / 64;
#pragma unroll
    for (int c = 0; c < NCH; ++c) {
      __syncthreads();
      if ((wr * (BM / 2)) / 64 == c) {
#pragma unroll
        for (int mi = 0; mi < MR; ++mi)
#pragma unroll
          for (int ni = 0; ni < NR; ++ni)
#pragma unroll
            for (int j = 0; j < 4; ++j) {
              const int rl = wr * (BM / 2) + mi * 16 + rl0 + j - c * 64;
              const int cc = wc * (BN / 2) + ni * 16 + cl;
              const int gn = n0 + cc;
              float v = acc[mi][ni][j];
              if ((FLAGS & GF_BIAS) && gn < N) v += bias[gn];
              Cs[rl * CST + cc] = v;
            }
      }
      __syncthreads();
      constexpr int CPR = BN / 4;
      constexpr int NIT = (64 * CPR) / 256;
#pragma unroll
      for (int i = 0; i < NIT; ++i) {
        const int ch = i * 256 + t;
        const int rr = ch / CPR, c4 = ch % CPR;
        const int gn = n0 + c4 * 4;
        const size_t gmr = (size_t)(m0 + c * 64 + rr);
        if (gn + 3 < N) {
          *(float4*)&((float*)Cout)[gmr * ldc + gn] = *(const float4*)&Cs[rr * CST + c4 * 4];
        } else {
#pragma unroll
          for (int c2 = 0; c2 < 4; ++c2)
            if (gn + c2 < N) ((float*)Cout)[gmr * ldc + gn + c2] = Cs[rr * CST + c4 * 4 + c2];
        }
      }
    }
  } else {
    constexpr int CST = BN + 8;
    unsigned short* Cs = (unsigned short*)smem;
    float ls0 = 0.f, ls1 = 0.f, ls2 = 0.f, ls3 = 0.f, ls4 = 0.f, ls5 = 0.f;
#pragma unroll
    for (int mi = 0; mi < MR; ++mi)
#pragma unroll
      for (int ni = 0; ni < NR; ++ni)
#pragma unroll
        for (int j = 0; j < 4; ++j) {
          const int rl = wr * (BM / 2) + mi * 16 + rl0 + j;
          const int cc = wc * (BN / 2) + ni * 16 + cl;
          const int gm = m0 + rl, gn = n0 + cc;
          const int srow = gm & (SS - 1);
          float v = acc[mi][ni][j];
          if ((FLAGS & GF_BIAS) && gn < N) v += bias[gn];
          if constexpr ((FLAGS & GF_RESID) != 0) {
            if constexpr (HASLNR) {
              if (gn < N) {
                float rv = b2f(Rz[(size_t)gm * ldc + gn]);
                const float wE = lnwT[(size_t)srow * DD + gn];
                const float bE = lnbT[(size_t)srow * DD + gn];
                rv = (rv - mu1) * rs1 * wE + bE;
                if constexpr (DBLR) rv = (rv - mu2) * rs2 * wE + bE;
                v += rv;
              }
            } else {
              v += b2f(Rz[(size_t)gm * ldc + gn]);
            }
          }
          if ((FLAGS & GF_POSENC) && gn < N) {
            float freq = expf(-(2.0f * gn / 224.0f) * 9.210340371976184f);
            float ang = (float)srow * freq;
            v += (gn & 1) ? cosf(ang) : sinf(ang);
          }
          if (FLAGS & GF_RELU) v = fmaxf(v, 0.f);
          if constexpr ((FLAGS & GF_STAT6) != 0) {
            if (gn < N) {
              const float wS = lnwS[(size_t)srow * DD + gn];
              const float bS = lnbS[(size_t)srow * DD + gn];
              const float wv = wS * v;
              ls0 += v; ls1 += v * v; ls2 += wv; ls3 += wS * wv;
              ls4 += wv * wv; ls5 += bS * wv;
            }
          }
          Cs[rl * CST + cc] = f2b(v);
        }
    __syncthreads();
#pragma unroll
    for (int it = 0; it < BM / 32; ++it) {
      const int rr = it * 32 + (t >> 3), qq = t & 7;
      const size_t gm = (size_t)(m0 + rr);
      *(uint4*)&((unsigned short*)Cout)[gm * ldc + n0 + qq * 8] =
          *(const uint4*)&Cs[rr * CST + qq * 8];
    }
    if constexpr ((FLAGS & GF_STAT6) != 0) {
      float s[6] = {ls0, ls1, ls2, ls3, ls4, ls5};
#pragma unroll
      for (int o2 = 32; o2 > 0; o2 >>= 1)
#pragma unroll
        for (int j = 0; j < 6; ++j) s[j] += __shfl_down(s[j], o2);
      if (l == 0)
#pragma unroll
        for (int j = 0; j < 6; ++j) red6[w * 6 + j] = s[j];
      __syncthreads();
      if (t < 6) {
        const float tot = red6[t] + red6[6 + t] + red6[12 + t] + red6[18 + t];
        atomicAdd(&statOut[(m0 >> 10) * 6 + t], tot);
      }
    }
  }
}

// ---------------------------------------------------------------------------
// Fused FFN, 512 threads = 8 waves, n-slices 80/80/32 per wave.
// ---------------------------------------------------------------------------
__global__ __launch_bounds__(512) void ffn_fused(
    const unsigned short* __restrict__ h2a,
    const unsigned short* __restrict__ W1t, const unsigned short* __restrict__ W2t,
    const unsigned short* __restrict__ W3t,
    const float* __restrict__ b1, const float* __restrict__ b2,
    const float* __restrict__ b3,
    const float* __restrict__ lnw, const float* __restrict__ lnb,
    const float* __restrict__ stA, float* __restrict__ statOut,
    unsigned short* __restrict__ Xout)
{
  __shared__ __align__(16) unsigned short sA[16 * 280];
  __shared__ __align__(16) unsigned short f1s[16 * 648];
  __shared__ __align__(16) unsigned short f2s[16 * 648];
  __shared__ float red6[48];
  const int t = threadIdx.x;
  const int l = t & 63, w = t >> 6;           // w in [0,8)
  const int cl = l & 15, g8 = (l >> 4) * 8, rl0 = (l >> 4) * 4;
  const int m0 = blockIdx.x * 16;
  const float* st = stA + (m0 >> 10) * 6;
  const float mu1 = st[0] * INV_SD;
  const float rs1 = rsqrtf(st[1] * INV_SD - mu1 * mu1 + 1e-5f);

  // stage sA = LN(h2a rows m0..m0+15); cols >= 224 zero (512 thr = 1 pass)
  {
    const int r = t >> 5, col = (t & 31) * 8;
    uint4 v = make_uint4(0u, 0u, 0u, 0u);
    if (col < DD) {
      const int srow = (m0 + r) & (SS - 1);
      uint4 raw = *(const uint4*)(h2a + (size_t)(m0 + r) * 256 + col);
      v = ln8(raw, lnw + (size_t)srow * DD + col, lnb + (size_t)srow * DD + col,
              mu1, rs1, 0.f, 1.f, false);
    }
    *(uint4*)(sA + r * 280 + col) = v;
  }
  __syncthreads();

  // phase 1: f1 = relu(LN(h2a) @ W1^T + b1), wave n-slice 80
  {
    f32x4 acc[5];
#pragma unroll
    for (int i = 0; i < 5; ++i) acc[i] = {0.f, 0.f, 0.f, 0.f};
    for (int ks = 0; ks < 8; ++ks) {
      const short8 af = *(const short8*)(sA + cl * 280 + ks * 32 + g8);
#pragma unroll
      for (int ni = 0; ni < 5; ++ni) {
        const int n = w * 80 + ni * 16 + cl;
        const short8 bf = *(const short8*)(W1t + (size_t)n * 256 + ks * 32 + g8);
        acc[ni] = __builtin_amdgcn_mfma_f32_16x16x32_bf16(af, bf, acc[ni], 0, 0, 0);
      }
    }
#pragma unroll
    for (int ni = 0; ni < 5; ++ni) {
      const int col = w * 80 + ni * 16 + cl;
      const float bias = (col < FFF) ? b1[col] : 0.f;
#pragma unroll
      for (int j = 0; j < 4; ++j)
        f1s[(rl0 + j) * 648 + col] = f2b(fmaxf(acc[ni][j] + bias, 0.f));
    }
  }
  __syncthreads();

  // phase 2: f2 = relu(f1 @ W2^T + b2)
  {
    f32x4 acc[5];
#pragma unroll
    for (int i = 0; i < 5; ++i) acc[i] = {0.f, 0.f, 0.f, 0.f};
    for (int ks = 0; ks < 20; ++ks) {
      const short8 af = *(const short8*)(f1s + cl * 648 + ks * 32 + g8);
#pragma unroll
      for (int ni = 0; ni < 5; ++ni) {
        const int n = w * 80 + ni * 16 + cl;
        const short8 bf = *(const short8*)(W2t + (size_t)n * 640 + ks * 32 + g8);
        acc[ni] = __builtin_amdgcn_mfma_f32_16x16x32_bf16(af, bf, acc[ni], 0, 0, 0);
      }
    }
#pragma unroll
    for (int ni = 0; ni < 5; ++ni) {
      const int col = w * 80 + ni * 16 + cl;
      const float bias = (col < FFF) ? b2[col] : 0.f;
#pragma unroll
      for (int j = 0; j < 4; ++j)
        f2s[(rl0 + j) * 648 + col] = f2b(fmaxf(acc[ni][j] + bias, 0.f));
    }
  }
  __syncthreads();

  // phase 3: X = f2 @ W3^T + b3 + LN(h2a) (fp32 from global); stats -> stB
  float s6[6] = {0.f, 0.f, 0.f, 0.f, 0.f, 0.f};
  {
    f32x4 acc[2];
#pragma unroll
    for (int i = 0; i < 2; ++i) acc[i] = {0.f, 0.f, 0.f, 0.f};
    for (int ks = 0; ks < 20; ++ks) {
      const short8 af = *(const short8*)(f2s + cl * 648 + ks * 32 + g8);
#pragma unroll
      for (int ni = 0; ni < 2; ++ni) {
        const int n = w * 32 + ni * 16 + cl;
        const short8 bf = *(const short8*)(W3t + (size_t)n * 640 + ks * 32 + g8);
        acc[ni] = __builtin_amdgcn_mfma_f32_16x16x32_bf16(af, bf, acc[ni], 0, 0, 0);
      }
    }
    unsigned short* Cs = sA;  // reuse (stride 280); last read was phase 1
#pragma unroll
    for (int ni = 0; ni < 2; ++ni) {
      const int col = w * 32 + ni * 16 + cl;
      const float bias = (col < DD) ? b3[col] : 0.f;
#pragma unroll
      for (int j = 0; j < 4; ++j) {
        const int gm = m0 + rl0 + j;
        const int srow = gm & (SS - 1);
        float v = acc[ni][j] + bias;
        if (col < DD) {
          const float wE = lnw[(size_t)srow * DD + col];
          const float bE = lnb[(size_t)srow * DD + col];
          v += (b2f(h2a[(size_t)gm * 256 + col]) - mu1) * rs1 * wE + bE;
          const float wv = wE * v;
          s6[0] += v; s6[1] += v * v; s6[2] += wv; s6[3] += wE * wv;
          s6[4] += wv * wv; s6[5] += bE * wv;
        }
        Cs[(rl0 + j) * 280 + col] = f2b(v);
      }
    }
  }
#pragma unroll
  for (int o2 = 32; o2 > 0; o2 >>= 1)
#pragma unroll
    for (int j2 = 0; j2 < 6; ++j2) s6[j2] += __shfl_down(s6[j2], o2);
  if (l == 0)
#pragma unroll
    for (int j2 = 0; j2 < 6; ++j2) red6[w * 6 + j2] = s6[j2];
  __syncthreads();
  if (t < 6) {
    float tot = 0.f;
#pragma unroll
    for (int ww = 0; ww < 8; ++ww) tot += red6[ww * 6 + t];
    atomicAdd(&statOut[(m0 >> 10) * 6 + t], tot);
  }
  {
    const int r = t >> 5, col = (t & 31) * 8;
    *(uint4*)(Xout + (size_t)(m0 + r) * 256 + col) = *(const uint4*)(sA + r * 280 + col);
  }
}

// ---------------------------------------------------------------------------
// Materialize hF = LN(LN(X)) for the logits GEMM (analytic LN2 stats).
// ---------------------------------------------------------------------------
__global__ __launch_bounds__(256) void ln2mat(
    const unsigned short* __restrict__ X, const float* __restrict__ lnw,
    const float* __restrict__ lnb, const float* __restrict__ st,
    const float* __restrict__ cst, unsigned short* __restrict__ Y)
{
  const int chunk = blockIdx.x * 256 + threadIdx.x;   // 131072 = 4096*32
  const int r = chunk >> 5, cc = chunk & 31;
  if (cc >= 28) {
    *(uint4*)(Y + (size_t)r * 256 + cc * 8) = make_uint4(0u, 0u, 0u, 0u);
    return;
  }
  const int b = r >> 10, srow = r & 1023;
  const float* s = st + b * 6;
  const float mu1 = s[0] * INV_SD;
  const float rs1 = rsqrtf(s[1] * INV_SD - mu1 * mu1 + 1e-5f);
  const float mu2 = (rs1 * (s[2] - mu1 * cst[0]) + cst[2]) * INV_SD;
  const float ey2 = (rs1 * rs1 * (s[4] - 2.f * mu1 * s[3] + mu1 * mu1 * cst[1]) +
                     2.f * rs1 * (s[5] - mu1 * cst[4]) + cst[3]) * INV_SD;
  const float rs2 = rsqrtf(ey2 - mu2 * mu2 + 1e-5f);
  uint4 raw = *(const uint4*)(X + (size_t)r * 256 + cc * 8);
  uint4 out = ln8(raw, lnw + (size_t)srow * DD + cc * 8, lnb + (size_t)srow * DD + cc * 8,
                  mu1, rs1, mu2, rs2, true);
  *(uint4*)(Y + (size_t)r * 256 + cc * 8) = out;
}

// ---------------------------------------------------------------------------
// Unified weight prep (6 tensors + lnconst) in one flat-grid dispatch.
// ---------------------------------------------------------------------------
__device__ __forceinline__ void prep_wt2_body(
    const float* __restrict__ W, unsigned short* __restrict__ O,
    int K, int N, int Kp, int Np, size_t sW, size_t sO, int tile, int ll,
    float* __restrict__ T /* [32][36] */)
{
  const int tx = Np >> 5;
  const int tn = tile % tx, tk = tile / tx;
  const int n0 = tn * 32, k0 = tk * 32;
  const float* Wl = W + sW * ll;
  unsigned short* Ol = O + sO * ll;
  {
    const int r = threadIdx.x >> 3, c4 = (threadIdx.x & 7) * 4;
    const int k = k0 + r, n = n0 + c4;
    float4 v = make_float4(0.f, 0.f, 0.f, 0.f);
    if (k < K) {
      if (n + 3 < N) v = *(const float4*)&Wl[(size_t)k * N + n];
      else {
        if (n + 0 < N) v.x = Wl[(size_t)k * N + n + 0];
        if (n + 1 < N) v.y = Wl[(size_t)k * N + n + 1];
        if (n + 2 < N) v.z = Wl[(size_t)k * N + n + 2];
        if (n + 3 < N) v.w = Wl[(size_t)k * N + n + 3];
      }
    }
    *(float4*)&T[r * 36 + c4] = v;
  }
  __syncthreads();
  {
    const int nl = threadIdx.x >> 3, k4 = (threadIdx.x & 7) * 4;
    ushort4 u;
    u.x = f2b(T[(k4 + 0) * 36 + nl]); u.y = f2b(T[(k4 + 1) * 36 + nl]);
    u.z = f2b(T[(k4 + 2) * 36 + nl]); u.w = f2b(T[(k4 + 3) * 36 + nl]);
    *(ushort4*)&Ol[(size_t)(n0 + nl) * Kp + k0 + k4] = u;
  }
}

__global__ __launch_bounds__(256) void prep_weights(
    const float* __restrict__ Wp, const float* __restrict__ Wo,
    const float* __restrict__ W1, const float* __restrict__ W2,
    const float* __restrict__ W3, const float* __restrict__ Wf,
    const float* __restrict__ lnw, const float* __restrict__ lnb,
    unsigned short* __restrict__ wpT, unsigned short* __restrict__ woT,
    unsigned short* __restrict__ w1T, unsigned short* __restrict__ w2T,
    unsigned short* __restrict__ w3T, unsigned short* __restrict__ wfT,
    float* __restrict__ cst)
{
  __shared__ float T[32 * 36];
  const int b = blockIdx.x;
  if (b < 192) {
    prep_wt2_body(Wp, wpT, 768, 224, 768, 256, 0, 0, b, 0, T);
  } else if (b < 704) {
    const int f = b - 192;
    prep_wt2_body(Wo, woT, 224, 224, 256, 256, (size_t)224 * 224, (size_t)256 * 256,
                  f % 64, f / 64, T);
  } else if (b < 1984) {
    const int f = b - 704;
    prep_wt2_body(W1, w1T, 224, 600, 256, 640, (size_t)224 * 600, (size_t)640 * 256,
                  f % 160, f / 160, T);
  } else if (b < 5184) {
    const int f = b - 1984;
    prep_wt2_body(W2, w2T, 600, 600, 640, 640, (size_t)600 * 600, (size_t)640 * 640,
                  f % 400, f / 400, T);
  } else if (b < 6464) {
    const int f = b - 5184;
    prep_wt2_body(W3, w3T, 600, 224, 640, 256, (size_t)600 * 224, (size_t)256 * 640,
                  f % 160, f / 160, T);
  } else if (b < 8480) {
    prep_wt2_body(Wf, wfT, 224, 8000, 256, 8064, 0, 0, b - 6464, 0, T);
  } else {
    // lnconst: per-layer Sw, Sw2, Sb, Sb2, Swb
    const int f = b - 8480;             // 512 blocks: g in [0,64), ll in [0,8)
    const int g = f & 63, ll = f >> 6;
    const float* wv = lnw + (size_t)ll * SD + g * 3584;
    const float* bv = lnb + (size_t)ll * SD + g * 3584;
    float s[5] = {0.f, 0.f, 0.f, 0.f, 0.f};
    for (int c = threadIdx.x * 4; c < 3584; c += 1024) {
      float4 w4 = *(const float4*)(wv + c);
      float4 b4 = *(const float4*)(bv + c);
      const float* wf2 = (const float*)&w4;
      const float* bf2 = (const float*)&b4;
#pragma unroll
      for (int e = 0; e < 4; ++e) {
        const float ww = wf2[e], bb = bf2[e];
        s[0] += ww; s[1] += ww * ww; s[2] += bb; s[3] += bb * bb; s[4] += ww * bb;
      }
    }
#pragma unroll
    for (int o2 = 32; o2 > 0; o2 >>= 1)
#pragma unroll
      for (int j = 0; j < 5; ++j) s[j] += __shfl_down(s[j], o2);
    float* red = T;   // reuse
    if ((threadIdx.x & 63) == 0)
#pragma unroll
      for (int j = 0; j < 5; ++j) red[(threadIdx.x >> 6) * 5 + j] = s[j];
    __syncthreads();
    if (threadIdx.x < 5) {
      const float tot = red[threadIdx.x] + red[5 + threadIdx.x] +
                        red[10 + threadIdx.x] + red[15 + threadIdx.x];
      atomicAdd(&cst[ll * 5 + threadIdx.x], tot);
    }
  }
}

// Coalesced-read qkv weight repack (dest pre-zeroed so pads stay 0).
__global__ void prep_wqkv(const float* __restrict__ Wq, const float* __restrict__ Wk,
                          const float* __restrict__ Wv, const float* __restrict__ bq,
                          const float* __restrict__ bk, const float* __restrict__ bv,
                          unsigned short* __restrict__ O, float* __restrict__ bcat)
{
  const int idx = blockIdx.x * 256 + threadIdx.x;
  if (idx < LLl * 8 * 224 * 28) {
    const int kk = idx % 28;
    const int d  = (idx / 28) % 224;
    const int h  = (idx / (28 * 224)) % 8;
    const int ll = idx / (28 * 224 * 8);
    const int col = h * 28 + kk;
    const size_t base = (size_t)ll * (704 * 256);
    O[base + (size_t)col * 256 + d]         = f2b(Wq[idx]);
    O[base + (size_t)(224 + col) * 256 + d] = f2b(Wk[idx]);
    O[base + (size_t)(448 + col) * 256 + d] = f2b(Wv[idx]);
  }
  if (idx < LLl * 8 * 28) {
    const int kk = idx % 28;
    const int h  = (idx / 28) % 8;
    const int ll = idx / (28 * 8);
    const int col = h * 28 + kk;
    bcat[ll * 672 + col]       = bq[idx];
    bcat[ll * 672 + 224 + col] = bk[idx];
    bcat[ll * 672 + 448 + col] = bv[idx];
  }
}

// x -> bf16; block 0 zeros the stats/cst region (424 floats, STRIDED — the
// region exceeds blockDim; a plain guard left atomic accumulators dirty
// across graph replays: round-10 failure).
__global__ void prep_x(const float* __restrict__ x, unsigned short* __restrict__ xb,
                       float* __restrict__ st)
{
  if (blockIdx.x == 0) {
    for (int i = threadIdx.x; i < 424; i += 256) st[i] = 0.f;
  }
  const size_t i = ((size_t)blockIdx.x * 256 + threadIdx.x) * 4;
  float4 v = *(const float4*)(x + i);
  ushort4 o;
  o.x = f2b(v.x); o.y = f2b(v.y); o.z = f2b(v.z); o.w = f2b(v.w);
  *(ushort4*)(xb + i) = o;
}

// ---------------------------------------------------------------------------
// MFMA flash attention, defer-max rescale (identity-skip, bit-exact).
// ---------------------------------------------------------------------------
__global__ __launch_bounds__(256) void attn_mfma(const unsigned short* __restrict__ qkv,
                                                 unsigned short* __restrict__ o)
{
  const int bh = blockIdx.x;
  const int qt = (int)gridDim.y - 1 - (int)blockIdx.y;
  const int b = bh >> 3, h = bh & 7;
  const int tid = threadIdx.x;
  const int w = tid >> 6, l = tid & 63;
  const int cl = l & 15, g = l >> 4;
  const int qbase = qt * 64 + w * 16;
  const float scale = 0.1889822365046136f;  // 1/sqrt(28)

  __shared__ unsigned short Ks[32 * 40];
  __shared__ unsigned short Vt[32 * 40];
  __shared__ unsigned short Ps[4][16 * 40];

  short8 aq;
  {
    const unsigned short* qp = qkv + ((size_t)(b * SS + qbase + cl)) * 704 + h * 28;
#pragma unroll
    for (int e = 0; e < 8; ++e) {
      const int d = g * 8 + e;
      ((unsigned short*)&aq)[e] = (d < 28) ? qp[d] : (unsigned short)0;
    }
  }

  f32x4 o0 = {0.f, 0.f, 0.f, 0.f}, o1 = {0.f, 0.f, 0.f, 0.f};
  float m[4] = {-INFINITY, -INFINITY, -INFINITY, -INFINITY};
  float lsum[4] = {0.f, 0.f, 0.f, 0.f};

  const int ntiles = qt * 2 + 2;
  const int ntw = ((qbase + 15) >> 5) + 1;

  const int sr = tid >> 3, sc4 = (tid & 7) << 2;
  const bool sact = (sc4 < 28);
  ushort4 ku = make_ushort4(0, 0, 0, 0), vu = make_ushort4(0, 0, 0, 0);
  if (sact) {
    const unsigned short* kp = qkv + ((size_t)(b * SS + sr)) * 704 + 224 + h * 28 + sc4;
    ku = *(const ushort4*)kp;
    vu = *(const ushort4*)(kp + 224);
  }

  for (int tile = 0; tile < ntiles; ++tile) {
    const int t0 = tile * 32;
    __syncthreads();
    *(ushort4*)&Ks[sr * 40 + sc4] = ku;
    Vt[(sc4 + 0) * 40 + sr] = vu.x;
    Vt[(sc4 + 1) * 40 + sr] = vu.y;
    Vt[(sc4 + 2) * 40 + sr] = vu.z;
    Vt[(sc4 + 3) * 40 + sr] = vu.w;
    __syncthreads();
    if (tile + 1 < ntiles && sact) {
      const unsigned short* kp =
          qkv + ((size_t)(b * SS + (tile + 1) * 32 + sr)) * 704 + 224 + h * 28 + sc4;
      ku = *(const ushort4*)kp;
      vu = *(const ushort4*)(kp + 224);
    }
    if (tile >= ntw) continue;

    const short8 bk0 = *(const short8*)&Ks[cl * 40 + g * 8];
    const short8 bk1 = *(const short8*)&Ks[(cl + 16) * 40 + g * 8];
    f32x4 zz = {0.f, 0.f, 0.f, 0.f};
    f32x4 s0 = __builtin_amdgcn_mfma_f32_16x16x32_bf16(aq, bk0, zz, 0, 0, 0);
    f32x4 s1 = __builtin_amdgcn_mfma_f32_16x16x32_bf16(aq, bk1, zz, 0, 0, 0);

    const bool diag = (t0 + 31 > qbase);
#pragma unroll
    for (int jj = 0; jj < 4; ++jj) {
      float v0 = s0[jj] * scale, v1 = s1[jj] * scale;
      if (diag) {
        const int qr = qbase + g * 4 + jj;
        if (t0 + cl > qr)      v0 = -INFINITY;
        if (t0 + 16 + cl > qr) v1 = -INFINITY;
      }
      float rm = fmaxf(v0, v1);
      rm = fmaxf(rm, __shfl_xor(rm, 1));
      rm = fmaxf(rm, __shfl_xor(rm, 2));
      rm = fmaxf(rm, __shfl_xor(rm, 4));
      rm = fmaxf(rm, __shfl_xor(rm, 8));
      if (rm > m[jj]) {           // skip identity rescale (exp(0)=1) otherwise
        const float r2 = __expf(m[jj] - rm);   // first tile: exp(-inf)=0
        m[jj] = rm;
        lsum[jj] *= r2;
        o0[jj] *= r2; o1[jj] *= r2;
      }
      const float e0 = __expf(v0 - m[jj]), e1 = __expf(v1 - m[jj]);
      lsum[jj] += e0 + e1;
      Ps[w][(g * 4 + jj) * 40 + cl]      = f2b(e0);
      Ps[w][(g * 4 + jj) * 40 + cl + 16] = f2b(e1);
    }
    const short8 pa  = *(const short8*)&Ps[w][cl * 40 + g * 8];
    const short8 bv0 = *(const short8*)&Vt[cl * 40 + g * 8];
    const short8 bv1 = *(const short8*)&Vt[(cl + 16) * 40 + g * 8];
    o0 = __builtin_amdgcn_mfma_f32_16x16x32_bf16(pa, bv0, o0, 0, 0, 0);
    o1 = __builtin_amdgcn_mfma_f32_16x16x32_bf16(pa, bv1, o1, 0, 0, 0);
  }

#pragma unroll
  for (int jj = 0; jj < 4; ++jj) {
    float ls = lsum[jj];
    ls += __shfl_xor(ls, 1);
    ls += __shfl_xor(ls, 2);
    ls += __shfl_xor(ls, 4);
    ls += __shfl_xor(ls, 8);
    const float inv = 1.0f / ls;
    const int row = qbase + g * 4 + jj;
    unsigned short* op = o + ((size_t)(b * SS + row)) * 256 + h * 28;
    op[cl] = f2b(o0[jj] * inv);
    if (cl < 12) op[16 + cl] = f2b(o1[jj] * inv);
  }
}

// ---------------------------------------------------------------------------
// Row softmax over V=8000, in place on d_out (fp32), float4 path.
// ---------------------------------------------------------------------------
__global__ __launch_bounds__(256) void softmax_rows(float* __restrict__ logits)
{
  const int row = blockIdx.x;
  float* p = logits + (size_t)row * VV;
  __shared__ float4 buf[VV / 4];
  __shared__ float red[4];
  const int tid = threadIdx.x;

  float mx = -INFINITY;
  for (int i = tid; i < VV / 4; i += 256) {
    float4 v = *(const float4*)(p + i * 4);
    buf[i] = v;
    mx = fmaxf(fmaxf(fmaxf(mx, v.x), fmaxf(v.y, v.z)), v.w);
  }
#pragma unroll
  for (int o2 = 32; o2 > 0; o2 >>= 1) mx = fmaxf(mx, __shfl_down(mx, o2));
  if ((tid & 63) == 0) red[tid >> 6] = mx;
  __syncthreads();
  mx = fmaxf(fmaxf(red[0], red[1]), fmaxf(red[2], red[3]));
  __syncthreads();

  float s = 0.f;
  for (int i = tid; i < VV / 4; i += 256) {
    float4 v = buf[i];
    v.x = __expf(v.x - mx); v.y = __expf(v.y - mx);
    v.z = __expf(v.z - mx); v.w = __expf(v.w - mx);
    buf[i] = v;
    s += v.x + v.y + v.z + v.w;
  }
#pragma unroll
  for (int o2 = 32; o2 > 0; o2 >>= 1) s += __shfl_down(s, o2);
  if ((tid & 63) == 0) red[tid >> 6] = s;
  __syncthreads();
  s = red[0] + red[1] + red[2] + red[3];
  const float inv = 1.0f / s;
  for (int i = tid; i < VV / 4; i += 256) {
    float4 v = buf[i];
    v.x *= inv; v.y *= inv; v.z *= inv; v.w *= inv;
    *(float4*)(p + i * 4) = v;
  }
}

// ---------------------------------------------------------------------------
extern "C" void kernel_launch(void* const* d_in, const int* in_sizes, int n_in,
                              void* d_out, int out_size, void* d_ws, size_t ws_size,
                              hipStream_t stream) {
  const float* x   = (const float*)d_in[0];
  const float* Wp  = (const float*)d_in[1];
  const float* bp  = (const float*)d_in[2];
  const float* Wq  = (const float*)d_in[3];
  const float* bq  = (const float*)d_in[4];
  const float* Wk  = (const float*)d_in[5];
  const float* bk  = (const float*)d_in[6];
  const float* Wv  = (const float*)d_in[7];
  const float* bv  = (const float*)d_in[8];
  const float* Wo  = (const float*)d_in[9];
  const float* bo  = (const float*)d_in[10];
  const float* W1  = (const float*)d_in[11];
  const float* b1  = (const float*)d_in[12];
  const float* W2  = (const float*)d_in[13];
  const float* b2  = (const float*)d_in[14];
  const float* W3  = (const float*)d_in[15];
  const float* b3  = (const float*)d_in[16];
  const float* lnw = (const float*)d_in[17];
  const float* lnb = (const float*)d_in[18];
  const float* Wf  = (const float*)d_in[19];
  const float* bf  = (const float*)d_in[20];

  unsigned short* wsb = (unsigned short*)d_ws;
  unsigned short* wpT   = wsb + WP;
  unsigned short* wqkvT = wsb + WQKV;
  unsigned short* woT   = wsb + WO;
  unsigned short* w1T   = wsb + W1T;
  unsigned short* w2T   = wsb + W2T;
  unsigned short* w3T   = wsb + W3T;
  unsigned short* wfT   = wsb + WFT;
  unsigned short* X     = wsb + HB;    // pre-LN layer state
  unsigned short* h2a   = wsb + H2B;   // attn-block output / hF
  unsigned short* obuf  = wsb + OBUF;
  unsigned short* xb    = wsb + BIG;
  unsigned short* qkvb  = wsb + BIG;
  float* bcat  = (float*)((char*)d_ws + FBYTE);
  float* stats = bcat + LLl * 672;      // 16 slots x 24 floats = 384
  float* cstA  = stats + 384;           // 8 layers x 5 floats = 40

  // ---- prep (3 dispatches + memset) ----
  hipMemsetAsync(wqkvT, 0, (size_t)LLl * 704 * 256 * 2, stream);
  prep_x<<<3072, 256, 0, stream>>>(x, xb, stats);   // block 0 zeros stats+cst (424)
  prep_wqkv<<<1568, 256, 0, stream>>>(Wq, Wk, Wv, bq, bk, bv, wqkvT, bcat);
  prep_weights<<<8992, 256, 0, stream>>>(Wp, Wo, W1, W2, W3, Wf, lnw, lnb,
                                         wpT, woT, w1T, w2T, w3T, wfT, cstA);

  // ---- proj + posenc: X = x @ Wp + bp + pe ----
  gemm_mfma<32, 64, GF_BIAS | GF_POSENC><<<dim3(4, 128), 256, 0, stream>>>(
      xb, wpT, bp, nullptr, X, 768, 224, 256,
      nullptr, nullptr, nullptr, nullptr, nullptr, nullptr, nullptr);

  for (int l = 0; l < LLl; ++l) {
    float* stA = stats + (size_t)(2 * l) * 24;
    float* stB = stats + (size_t)(2 * l + 1) * 24;
    const float* stPrev = stats + (size_t)(2 * l - 1) * 24;   // stB_{l-1}, l>=1
    const float* lnwP = lnw + (size_t)(l - 1) * SD;           // layer l-1 params
    const float* lnbP = lnb + (size_t)(l - 1) * SD;
    const float* cstP = cstA + (l - 1) * 5;
    const float* lnwL = lnw + (size_t)l * SD;
    const float* lnbL = lnb + (size_t)l * SD;

    // 1. qkv = LNLN(X) @ Wqkv + bqkv   (layer 0: plain X)
    if (l == 0) {
      gemm_mfma<64, 64, GF_BIAS><<<dim3(11, 64), 256, 0, stream>>>(
          X, wqkvT, bcat, nullptr, qkvb, 256, 672, 704,
          nullptr, nullptr, nullptr, nullptr, nullptr, nullptr, nullptr);
    } else {
      gemm_mfma<64, 64, GF_BIAS | GF_LNA2><<<dim3(11, 64), 256, 0, stream>>>(
          X, wqkvT + (size_t)l * 704 * 256, bcat + l * 672, nullptr, qkvb, 256, 672, 704,
          lnwP, lnbP, stPrev, cstP, nullptr, nullptr, nullptr);
    }
    // 2. attention
    attn_mfma<<<dim3(BB * 8, SS / 64), 256, 0, stream>>>(qkvb, obuf);
    // 3. h2a = obuf @ Wo + bo + LNLN(X); stat6 -> stA
    if (l == 0) {
      gemm_mfma<32, 64, GF_BIAS | GF_RESID | GF_STAT6><<<dim3(4, 128), 256, 0, stream>>>(
          obuf, woT, bo, X, h2a, 256, 224, 256,
          nullptr, nullptr, nullptr, nullptr, lnwL, lnbL, stA);
    } else {
      gemm_mfma<32, 64, GF_BIAS | GF_RESID | GF_LNRES2 | GF_STAT6>
          <<<dim3(4, 128), 256, 0, stream>>>(
          obuf, woT + (size_t)l * 256 * 256, bo + (size_t)l * 224, X, h2a, 256, 224, 256,
          lnwP, lnbP, stPrev, cstP, lnwL, lnbL, stA);
    }
    // 4. fused FFN: X = relu(relu(LN(h2a)@W1)@W2)@W3 + b3 + LN(h2a); stat6 -> stB
    ffn_fused<<<256, 512, 0, stream>>>(
        h2a, w1T + (size_t)l * 640 * 256, w2T + (size_t)l * 640 * 640,
        w3T + (size_t)l * 256 * 640, b1 + (size_t)l * 600, b2 + (size_t)l * 600,
        b3 + (size_t)l * 224, lnwL, lnbL, stA, stB, X);
  }

  // ---- hF = LNLN(X; stB7) materialized once, logits, softmax ----
  ln2mat<<<512, 256, 0, stream>>>(X, lnw + (size_t)7 * SD, lnb + (size_t)7 * SD,
                                  stats + (size_t)15 * 24, cstA + 7 * 5, h2a);
  gemm_mfma<128, 128, GF_BIAS | GF_F32OUT | GF_SWAP><<<dim3(32, 63), 256, 0, stream>>>(
      h2a, wfT, bf, nullptr, (float*)d_out, 256, 8000, 8000,
      nullptr, nullptr, nullptr, nullptr, nullptr, nullptr, nullptr);
  softmax_rows<<<4096, 256, 0, stream>>>((float*)d_out);
}

// Round 15
// 1247.741 us; speedup vs baseline: 1.3798x; 1.0008x over previous
//
#include <hip/hip_runtime.h>
#include <math.h>

#define GF_BIAS   1
#define GF_RELU   2
#define GF_RESID  4
#define GF_POSENC 8
#define GF_F32OUT 16
#define GF_STAT6  32
#define GF_SWAP   64
#define GF_LNA    128
#define GF_LNA2   256
#define GF_LNRES  512
#define GF_LNRES2 1024

namespace {
constexpr int BB = 4, SS = 1024, DD = 224, FFF = 600, VV = 8000, LLl = 8;
constexpr int SD = SS * DD;  // 229376
constexpr float INV_SD = 1.0f / (float)SD;

// workspace layout, bf16 element offsets
constexpr size_t WP   = 0;                         // [256][768]
constexpr size_t WQKV = WP + (size_t)256 * 768;    // L x [704][256]
constexpr size_t WO   = WQKV + (size_t)LLl * 704 * 256;
constexpr size_t W1T  = WO + (size_t)LLl * 256 * 256;
constexpr size_t W2T  = W1T + (size_t)LLl * 640 * 256;
constexpr size_t W3T  = W2T + (size_t)LLl * 640 * 640;
constexpr size_t WFT  = W3T + (size_t)LLl * 256 * 640;   // [8064][256]
constexpr size_t HB   = WFT + (size_t)8064 * 256;        // X (pre-LN state)
constexpr size_t H2B  = HB + (size_t)4096 * 256;         // h2a / hF
constexpr size_t OBUF = H2B + (size_t)4096 * 256;
constexpr size_t BIG  = OBUF + (size_t)4096 * 256;       // xb | qkv
constexpr size_t ENDB = BIG + (size_t)2 * 4096 * 640;
constexpr size_t FBYTE = ENDB * 2;                       // float region byte offset
}

using short8 = __attribute__((ext_vector_type(8))) short;
using f32x4  = __attribute__((ext_vector_type(4))) float;

__device__ __forceinline__ float bits2f(unsigned u) {
  union { unsigned u; float f; } v; v.u = u; return v.f;
}
__device__ __forceinline__ unsigned short f2b(float f) {
  union { float f; unsigned u; } v; v.f = f;
  unsigned r = v.u + 0x7FFFu + ((v.u >> 16) & 1u);
  return (unsigned short)(r >> 16);
}
__device__ __forceinline__ float b2f(unsigned short b) {
  return bits2f((unsigned)b << 16);
}

// LN-transform 8 bf16 elements (one 16B chunk) with per-element w,b.
__device__ __forceinline__ uint4 ln8(uint4 raw, const float* __restrict__ wp,
                                     const float* __restrict__ bp,
                                     float mu1, float rs1, float mu2, float rs2,
                                     bool dbl) {
  float4 w0 = *(const float4*)wp, w1v = *(const float4*)(wp + 4);
  float4 b0 = *(const float4*)bp, b1v = *(const float4*)(bp + 4);
  float wv[8] = {w0.x, w0.y, w0.z, w0.w, w1v.x, w1v.y, w1v.z, w1v.w};
  float bv[8] = {b0.x, b0.y, b0.z, b0.w, b1v.x, b1v.y, b1v.z, b1v.w};
  const unsigned* u = (const unsigned*)&raw;
  uint4 out;
  unsigned* ou = (unsigned*)&out;
#pragma unroll
  for (int q = 0; q < 4; ++q) {
    float x0 = bits2f(u[q] << 16), x1 = bits2f(u[q] & 0xFFFF0000u);
    float y0 = (x0 - mu1) * rs1 * wv[q * 2] + bv[q * 2];
    float y1 = (x1 - mu1) * rs1 * wv[q * 2 + 1] + bv[q * 2 + 1];
    if (dbl) {
      y0 = (y0 - mu2) * rs2 * wv[q * 2] + bv[q * 2];
      y1 = (y1 - mu2) * rs2 * wv[q * 2 + 1] + bv[q * 2 + 1];
    }
    ou[q] = (unsigned)f2b(y0) | ((unsigned)f2b(y1) << 16);
  }
  return out;
}

// ---------------------------------------------------------------------------
// bf16 MFMA GEMM with fused LN transforms and 6-sum stat epilogue.
// ---------------------------------------------------------------------------
template <int BM, int BN, int FLAGS>
__global__ __launch_bounds__(256) void gemm_mfma(
    const unsigned short* __restrict__ A, const unsigned short* __restrict__ Bt,
    const float* __restrict__ bias, const unsigned short* __restrict__ Rz,
    void* __restrict__ Cout, int Kp, int N, int ldc,
    const float* __restrict__ lnwT, const float* __restrict__ lnbT,
    const float* __restrict__ stIn, const float* __restrict__ cst,
    const float* __restrict__ lnwS, const float* __restrict__ lnbS,
    float* __restrict__ statOut)
{
  constexpr bool HASLNA = (FLAGS & (GF_LNA | GF_LNA2)) != 0;
  constexpr bool HASLNR = (FLAGS & (GF_LNRES | GF_LNRES2)) != 0;
  constexpr bool DBLA = (FLAGS & GF_LNA2) != 0;
  constexpr bool DBLR = (FLAGS & GF_LNRES2) != 0;
  constexpr int MR = BM / 32, NR = BN / 32;
  constexpr int APT = BM / 32, BPT = BN / 32;
  constexpr int ABY = BM * 128, BBY = BN * 128;   // bytes (BK=64)
  constexpr int CBY = (FLAGS & GF_F32OUT) ? (64 * (BN + 4) * 4) : (BM * (BN + 8) * 2);
  constexpr int SBY = (ABY + BBY) > CBY ? (ABY + BBY) : CBY;
  __shared__ __align__(16) char smem[SBY];
  __shared__ float red6[24];
  unsigned short* sA = (unsigned short*)smem;
  unsigned short* sB = (unsigned short*)(smem + ABY);
  const int t = threadIdx.x;
  const int l = t & 63;
  const int w = t >> 6, wr = w >> 1, wc = w & 1;
  const int m0 = ((FLAGS & GF_SWAP) ? blockIdx.x : blockIdx.y) * BM;
  const int n0 = ((FLAGS & GF_SWAP) ? blockIdx.y : blockIdx.x) * BN;
  const int nk = Kp >> 6;

  float mu1 = 0.f, rs1 = 1.f, mu2 = 0.f, rs2 = 1.f;
  if constexpr (HASLNA || HASLNR) {
    const float* st = stIn + (m0 >> 10) * 6;
    const float s0 = st[0], s1 = st[1];
    mu1 = s0 * INV_SD;
    rs1 = rsqrtf(s1 * INV_SD - mu1 * mu1 + 1e-5f);
    if constexpr (DBLA || DBLR) {
      const float swx = st[2], sw2x = st[3], sw2x2 = st[4], swbx = st[5];
      mu2 = (rs1 * (swx - mu1 * cst[0]) + cst[2]) * INV_SD;
      const float ey2 = (rs1 * rs1 * (sw2x2 - 2.f * mu1 * sw2x + mu1 * mu1 * cst[1]) +
                         2.f * rs1 * (swbx - mu1 * cst[4]) + cst[3]) * INV_SD;
      rs2 = rsqrtf(ey2 - mu2 * mu2 + 1e-5f);
    }
  }

  int aoff[APT], ar[APT], ac[APT];
#pragma unroll
  for (int p = 0; p < APT; ++p) {
    int off = (t + p * 256) * 16;
    int r = off >> 7;
    int cb = (off & 127) ^ ((r & 7) << 4);
    aoff[p] = off; ar[p] = r; ac[p] = cb >> 1;
  }
  int boff[BPT], br[BPT], bc[BPT];
#pragma unroll
  for (int p = 0; p < BPT; ++p) {
    int off = (t + p * 256) * 16;
    int r = off >> 7;
    int cb = (off & 127) ^ ((r & 7) << 4);
    boff[p] = off; br[p] = r; bc[p] = cb >> 1;
  }

  const unsigned short* Ab = A + (size_t)m0 * Kp;
  const unsigned short* Bb = Bt + (size_t)n0 * Kp;

  auto loadA = [&](int p, int kb) -> uint4 {
    const int d0 = kb + ac[p];
    uint4 raw = *(const uint4*)(Ab + (size_t)ar[p] * Kp + d0);
    if constexpr (HASLNA) {
      if (d0 >= DD) return make_uint4(0u, 0u, 0u, 0u);
      const int srow = (m0 + ar[p]) & (SS - 1);
      raw = ln8(raw, lnwT + (size_t)srow * DD + d0, lnbT + (size_t)srow * DD + d0,
                mu1, rs1, mu2, rs2, DBLA);
    }
    return raw;
  };

  uint4 ra[APT], rb[BPT];
#pragma unroll
  for (int p = 0; p < APT; ++p) ra[p] = loadA(p, 0);
#pragma unroll
  for (int p = 0; p < BPT; ++p) rb[p] = *(const uint4*)(Bb + (size_t)br[p] * Kp + bc[p]);

  f32x4 acc[MR][NR];
#pragma unroll
  for (int i = 0; i < MR; ++i)
#pragma unroll
    for (int j = 0; j < NR; ++j) acc[i][j] = {0.f, 0.f, 0.f, 0.f};

  for (int kt = 0; kt < nk; ++kt) {
#pragma unroll
    for (int p = 0; p < APT; ++p) *(uint4*)((char*)sA + aoff[p]) = ra[p];
#pragma unroll
    for (int p = 0; p < BPT; ++p) *(uint4*)((char*)sB + boff[p]) = rb[p];
    __syncthreads();
    if (kt + 1 < nk) {
      const int k1 = (kt + 1) * 64;
#pragma unroll
      for (int p = 0; p < APT; ++p) ra[p] = loadA(p, k1);
#pragma unroll
      for (int p = 0; p < BPT; ++p) rb[p] = *(const uint4*)(Bb + (size_t)br[p] * Kp + k1 + bc[p]);
    }
#pragma unroll
    for (int kh = 0; kh < 2; ++kh) {
      short8 af[MR], bfg[NR];
#pragma unroll
      for (int mi = 0; mi < MR; ++mi) {
        const int row = wr * (BM / 2) + mi * 16 + (l & 15);
        const int byte = (row * 128 + kh * 64 + (l >> 4) * 16) ^ ((row & 7) << 4);
        af[mi] = *(const short8*)((const char*)sA + byte);
      }
#pragma unroll
      for (int ni = 0; ni < NR; ++ni) {
        const int row = wc * (BN / 2) + ni * 16 + (l & 15);
        const int byte = (row * 128 + kh * 64 + (l >> 4) * 16) ^ ((row & 7) << 4);
        bfg[ni] = *(const short8*)((const char*)sB + byte);
      }
#pragma unroll
      for (int mi = 0; mi < MR; ++mi)
#pragma unroll
        for (int ni = 0; ni < NR; ++ni)
          acc[mi][ni] = __builtin_amdgcn_mfma_f32_16x16x32_bf16(af[mi], bfg[ni], acc[mi][ni], 0, 0, 0);
    }
    __syncthreads();
  }

  const int cl = l & 15, rl0 = (l >> 4) * 4;

  if constexpr ((FLAGS & GF_F32OUT) != 0) {
    constexpr int CST = BN + 4;
    float* Cs = (float*)smem;
    constexpr int NCH = BM / 64;
#pragma unroll
    for (int c = 0; c < NCH; ++c) {
      __syncthreads();
      if ((wr * (BM / 2)) / 64 == c) {
#pragma unroll
        for (int mi = 0; mi < MR; ++mi)
#pragma unroll
          for (int ni = 0; ni < NR; ++ni)
#pragma unroll
            for (int j = 0; j < 4; ++j) {
              const int rl = wr * (BM / 2) + mi * 16 + rl0 + j - c * 64;
              const int cc = wc * (BN / 2) + ni * 16 + cl;
              const int gn = n0 + cc;
              float v = acc[mi][ni][j];
              if ((FLAGS & GF_BIAS) && gn < N) v += bias[gn];
              Cs[rl * CST + cc] = v;
            }
      }
      __syncthreads();
      constexpr int CPR = BN / 4;
      constexpr int NIT = (64 * CPR) / 256;
#pragma unroll
      for (int i = 0; i < NIT; ++i) {
        const int ch = i * 256 + t;
        const int rr = ch / CPR, c4 = ch % CPR;
        const int gn = n0 + c4 * 4;
        const size_t gmr = (size_t)(m0 + c * 64 + rr);
        if (gn + 3 < N) {
          *(float4*)&((float*)Cout)[gmr * ldc + gn] = *(const float4*)&Cs[rr * CST + c4 * 4];
        } else {
#pragma unroll
          for (int c2 = 0; c2 < 4; ++c2)
            if (gn + c2 < N) ((float*)Cout)[gmr * ldc + gn + c2] = Cs[rr * CST + c4 * 4 + c2];
        }
      }
    }
  } else {
    constexpr int CST = BN + 8;
    unsigned short* Cs = (unsigned short*)smem;
    float ls0 = 0.f, ls1 = 0.f, ls2 = 0.f, ls3 = 0.f, ls4 = 0.f, ls5 = 0.f;
#pragma unroll
    for (int mi = 0; mi < MR; ++mi)
#pragma unroll
      for (int ni = 0; ni < NR; ++ni)
#pragma unroll
        for (int j = 0; j < 4; ++j) {
          const int rl = wr * (BM / 2) + mi * 16 + rl0 + j;
          const int cc = wc * (BN / 2) + ni * 16 + cl;
          const int gm = m0 + rl, gn = n0 + cc;
          const int srow = gm & (SS - 1);
          float v = acc[mi][ni][j];
          if ((FLAGS & GF_BIAS) && gn < N) v += bias[gn];
          if constexpr ((FLAGS & GF_RESID) != 0) {
            if constexpr (HASLNR) {
              if (gn < N) {
                float rv = b2f(Rz[(size_t)gm * ldc + gn]);
                const float wE = lnwT[(size_t)srow * DD + gn];
                const float bE = lnbT[(size_t)srow * DD + gn];
                rv = (rv - mu1) * rs1 * wE + bE;
                if constexpr (DBLR) rv = (rv - mu2) * rs2 * wE + bE;
                v += rv;
              }
            } else {
              v += b2f(Rz[(size_t)gm * ldc + gn]);
            }
          }
          if ((FLAGS & GF_POSENC) && gn < N) {
            float freq = expf(-(2.0f * gn / 224.0f) * 9.210340371976184f);
            float ang = (float)srow * freq;
            v += (gn & 1) ? cosf(ang) : sinf(ang);
          }
          if (FLAGS & GF_RELU) v = fmaxf(v, 0.f);
          if constexpr ((FLAGS & GF_STAT6) != 0) {
            if (gn < N) {
              const float wS = lnwS[(size_t)srow * DD + gn];
              const float bS = lnbS[(size_t)srow * DD + gn];
              const float wv = wS * v;
              ls0 += v; ls1 += v * v; ls2 += wv; ls3 += wS * wv;
              ls4 += wv * wv; ls5 += bS * wv;
            }
          }
          Cs[rl * CST + cc] = f2b(v);
        }
    __syncthreads();
#pragma unroll
    for (int it = 0; it < BM / 32; ++it) {
      const int rr = it * 32 + (t >> 3), qq = t & 7;
      const size_t gm = (size_t)(m0 + rr);
      *(uint4*)&((unsigned short*)Cout)[gm * ldc + n0 + qq * 8] =
          *(const uint4*)&Cs[rr * CST + qq * 8];
    }
    if constexpr ((FLAGS & GF_STAT6) != 0) {
      float s[6] = {ls0, ls1, ls2, ls3, ls4, ls5};
#pragma unroll
      for (int o2 = 32; o2 > 0; o2 >>= 1)
#pragma unroll
        for (int j = 0; j < 6; ++j) s[j] += __shfl_down(s[j], o2);
      if (l == 0)
#pragma unroll
        for (int j = 0; j < 6; ++j) red6[w * 6 + j] = s[j];
      __syncthreads();
      if (t < 6) {
        const float tot = red6[t] + red6[6 + t] + red6[12 + t] + red6[18 + t];
        atomicAdd(&statOut[(m0 >> 10) * 6 + t], tot);
      }
    }
  }
}

// ---------------------------------------------------------------------------
// Fused FFN, 512 threads = 8 waves, n-slices 80/80/32 per wave.
// ---------------------------------------------------------------------------
__global__ __launch_bounds__(512) void ffn_fused(
    const unsigned short* __restrict__ h2a,
    const unsigned short* __restrict__ W1t, const unsigned short* __restrict__ W2t,
    const unsigned short* __restrict__ W3t,
    const float* __restrict__ b1, const float* __restrict__ b2,
    const float* __restrict__ b3,
    const float* __restrict__ lnw, const float* __restrict__ lnb,
    const float* __restrict__ stA, float* __restrict__ statOut,
    unsigned short* __restrict__ Xout)
{
  __shared__ __align__(16) unsigned short sA[16 * 280];
  __shared__ __align__(16) unsigned short f1s[16 * 648];
  __shared__ __align__(16) unsigned short f2s[16 * 648];
  __shared__ float red6[48];
  const int t = threadIdx.x;
  const int l = t & 63, w = t >> 6;           // w in [0,8)
  const int cl = l & 15, g8 = (l >> 4) * 8, rl0 = (l >> 4) * 4;
  const int m0 = blockIdx.x * 16;
  const float* st = stA + (m0 >> 10) * 6;
  const float mu1 = st[0] * INV_SD;
  const float rs1 = rsqrtf(st[1] * INV_SD - mu1 * mu1 + 1e-5f);

  // stage sA = LN(h2a rows m0..m0+15); cols >= 224 zero (512 thr = 1 pass)
  {
    const int r = t >> 5, col = (t & 31) * 8;
    uint4 v = make_uint4(0u, 0u, 0u, 0u);
    if (col < DD) {
      const int srow = (m0 + r) & (SS - 1);
      uint4 raw = *(const uint4*)(h2a + (size_t)(m0 + r) * 256 + col);
      v = ln8(raw, lnw + (size_t)srow * DD + col, lnb + (size_t)srow * DD + col,
              mu1, rs1, 0.f, 1.f, false);
    }
    *(uint4*)(sA + r * 280 + col) = v;
  }
  __syncthreads();

  // phase 1: f1 = relu(LN(h2a) @ W1^T + b1), wave n-slice 80
  {
    f32x4 acc[5];
#pragma unroll
    for (int i = 0; i < 5; ++i) acc[i] = {0.f, 0.f, 0.f, 0.f};
    for (int ks = 0; ks < 8; ++ks) {
      const short8 af = *(const short8*)(sA + cl * 280 + ks * 32 + g8);
#pragma unroll
      for (int ni = 0; ni < 5; ++ni) {
        const int n = w * 80 + ni * 16 + cl;
        const short8 bf = *(const short8*)(W1t + (size_t)n * 256 + ks * 32 + g8);
        acc[ni] = __builtin_amdgcn_mfma_f32_16x16x32_bf16(af, bf, acc[ni], 0, 0, 0);
      }
    }
#pragma unroll
    for (int ni = 0; ni < 5; ++ni) {
      const int col = w * 80 + ni * 16 + cl;
      const float bias = (col < FFF) ? b1[col] : 0.f;
#pragma unroll
      for (int j = 0; j < 4; ++j)
        f1s[(rl0 + j) * 648 + col] = f2b(fmaxf(acc[ni][j] + bias, 0.f));
    }
  }
  __syncthreads();

  // phase 2: f2 = relu(f1 @ W2^T + b2)
  {
    f32x4 acc[5];
#pragma unroll
    for (int i = 0; i < 5; ++i) acc[i] = {0.f, 0.f, 0.f, 0.f};
    for (int ks = 0; ks < 20; ++ks) {
      const short8 af = *(const short8*)(f1s + cl * 648 + ks * 32 + g8);
#pragma unroll
      for (int ni = 0; ni < 5; ++ni) {
        const int n = w * 80 + ni * 16 + cl;
        const short8 bf = *(const short8*)(W2t + (size_t)n * 640 + ks * 32 + g8);
        acc[ni] = __builtin_amdgcn_mfma_f32_16x16x32_bf16(af, bf, acc[ni], 0, 0, 0);
      }
    }
#pragma unroll
    for (int ni = 0; ni < 5; ++ni) {
      const int col = w * 80 + ni * 16 + cl;
      const float bias = (col < FFF) ? b2[col] : 0.f;
#pragma unroll
      for (int j = 0; j < 4; ++j)
        f2s[(rl0 + j) * 648 + col] = f2b(fmaxf(acc[ni][j] + bias, 0.f));
    }
  }
  __syncthreads();

  // phase 3: X = f2 @ W3^T + b3 + LN(h2a) (fp32 from global); stats -> stB
  float s6[6] = {0.f, 0.f, 0.f, 0.f, 0.f, 0.f};
  {
    f32x4 acc[2];
#pragma unroll
    for (int i = 0; i < 2; ++i) acc[i] = {0.f, 0.f, 0.f, 0.f};
    for (int ks = 0; ks < 20; ++ks) {
      const short8 af = *(const short8*)(f2s + cl * 648 + ks * 32 + g8);
#pragma unroll
      for (int ni = 0; ni < 2; ++ni) {
        const int n = w * 32 + ni * 16 + cl;
        const short8 bf = *(const short8*)(W3t + (size_t)n * 640 + ks * 32 + g8);
        acc[ni] = __builtin_amdgcn_mfma_f32_16x16x32_bf16(af, bf, acc[ni], 0, 0, 0);
      }
    }
    unsigned short* Cs = sA;  // reuse (stride 280); last read was phase 1
#pragma unroll
    for (int ni = 0; ni < 2; ++ni) {
      const int col = w * 32 + ni * 16 + cl;
      const float bias = (col < DD) ? b3[col] : 0.f;
#pragma unroll
      for (int j = 0; j < 4; ++j) {
        const int gm = m0 + rl0 + j;
        const int srow = gm & (SS - 1);
        float v = acc[ni][j] + bias;
        if (col < DD) {
          const float wE = lnw[(size_t)srow * DD + col];
          const float bE = lnb[(size_t)srow * DD + col];
          v += (b2f(h2a[(size_t)gm * 256 + col]) - mu1) * rs1 * wE + bE;
          const float wv = wE * v;
          s6[0] += v; s6[1] += v * v; s6[2] += wv; s6[3] += wE * wv;
          s6[4] += wv * wv; s6[5] += bE * wv;
        }
        Cs[(rl0 + j) * 280 + col] = f2b(v);
      }
    }
  }
#pragma unroll
  for (int o2 = 32; o2 > 0; o2 >>= 1)
#pragma unroll
    for (int j2 = 0; j2 < 6; ++j2) s6[j2] += __shfl_down(s6[j2], o2);
  if (l == 0)
#pragma unroll
    for (int j2 = 0; j2 < 6; ++j2) red6[w * 6 + j2] = s6[j2];
  __syncthreads();
  if (t < 6) {
    float tot = 0.f;
#pragma unroll
    for (int ww = 0; ww < 8; ++ww) tot += red6[ww * 6 + t];
    atomicAdd(&statOut[(m0 >> 10) * 6 + t], tot);
  }
  {
    const int r = t >> 5, col = (t & 31) * 8;
    *(uint4*)(Xout + (size_t)(m0 + r) * 256 + col) = *(const uint4*)(sA + r * 280 + col);
  }
}

// ---------------------------------------------------------------------------
// Materialize hF = LN(LN(X)) for the logits GEMM (analytic LN2 stats).
// ---------------------------------------------------------------------------
__global__ __launch_bounds__(256) void ln2mat(
    const unsigned short* __restrict__ X, const float* __restrict__ lnw,
    const float* __restrict__ lnb, const float* __restrict__ st,
    const float* __restrict__ cst, unsigned short* __restrict__ Y)
{
  const int chunk = blockIdx.x * 256 + threadIdx.x;   // 131072 = 4096*32
  const int r = chunk >> 5, cc = chunk & 31;
  if (cc >= 28) {
    *(uint4*)(Y + (size_t)r * 256 + cc * 8) = make_uint4(0u, 0u, 0u, 0u);
    return;
  }
  const int b = r >> 10, srow = r & 1023;
  const float* s = st + b * 6;
  const float mu1 = s[0] * INV_SD;
  const float rs1 = rsqrtf(s[1] * INV_SD - mu1 * mu1 + 1e-5f);
  const float mu2 = (rs1 * (s[2] - mu1 * cst[0]) + cst[2]) * INV_SD;
  const float ey2 = (rs1 * rs1 * (s[4] - 2.f * mu1 * s[3] + mu1 * mu1 * cst[1]) +
                     2.f * rs1 * (s[5] - mu1 * cst[4]) + cst[3]) * INV_SD;
  const float rs2 = rsqrtf(ey2 - mu2 * mu2 + 1e-5f);
  uint4 raw = *(const uint4*)(X + (size_t)r * 256 + cc * 8);
  uint4 out = ln8(raw, lnw + (size_t)srow * DD + cc * 8, lnb + (size_t)srow * DD + cc * 8,
                  mu1, rs1, mu2, rs2, true);
  *(uint4*)(Y + (size_t)r * 256 + cc * 8) = out;
}

// ---------------------------------------------------------------------------
// Unified weight prep (6 tensors + lnconst) in one flat-grid dispatch.
// ---------------------------------------------------------------------------
__device__ __forceinline__ void prep_wt2_body(
    const float* __restrict__ W, unsigned short* __restrict__ O,
    int K, int N, int Kp, int Np, size_t sW, size_t sO, int tile, int ll,
    float* __restrict__ T /* [32][36] */)
{
  const int tx = Np >> 5;
  const int tn = tile % tx, tk = tile / tx;
  const int n0 = tn * 32, k0 = tk * 32;
  const float* Wl = W + sW * ll;
  unsigned short* Ol = O + sO * ll;
  {
    const int r = threadIdx.x >> 3, c4 = (threadIdx.x & 7) * 4;
    const int k = k0 + r, n = n0 + c4;
    float4 v = make_float4(0.f, 0.f, 0.f, 0.f);
    if (k < K) {
      if (n + 3 < N) v = *(const float4*)&Wl[(size_t)k * N + n];
      else {
        if (n + 0 < N) v.x = Wl[(size_t)k * N + n + 0];
        if (n + 1 < N) v.y = Wl[(size_t)k * N + n + 1];
        if (n + 2 < N) v.z = Wl[(size_t)k * N + n + 2];
        if (n + 3 < N) v.w = Wl[(size_t)k * N + n + 3];
      }
    }
    *(float4*)&T[r * 36 + c4] = v;
  }
  __syncthreads();
  {
    const int nl = threadIdx.x >> 3, k4 = (threadIdx.x & 7) * 4;
    ushort4 u;
    u.x = f2b(T[(k4 + 0) * 36 + nl]); u.y = f2b(T[(k4 + 1) * 36 + nl]);
    u.z = f2b(T[(k4 + 2) * 36 + nl]); u.w = f2b(T[(k4 + 3) * 36 + nl]);
    *(ushort4*)&Ol[(size_t)(n0 + nl) * Kp + k0 + k4] = u;
  }
}

__global__ __launch_bounds__(256) void prep_weights(
    const float* __restrict__ Wp, const float* __restrict__ Wo,
    const float* __restrict__ W1, const float* __restrict__ W2,
    const float* __restrict__ W3, const float* __restrict__ Wf,
    const float* __restrict__ lnw, const float* __restrict__ lnb,
    unsigned short* __restrict__ wpT, unsigned short* __restrict__ woT,
    unsigned short* __restrict__ w1T, unsigned short* __restrict__ w2T,
    unsigned short* __restrict__ w3T, unsigned short* __restrict__ wfT,
    float* __restrict__ cst)
{
  __shared__ float T[32 * 36];
  const int b = blockIdx.x;
  if (b < 192) {
    prep_wt2_body(Wp, wpT, 768, 224, 768, 256, 0, 0, b, 0, T);
  } else if (b < 704) {
    const int f = b - 192;
    prep_wt2_body(Wo, woT, 224, 224, 256, 256, (size_t)224 * 224, (size_t)256 * 256,
                  f % 64, f / 64, T);
  } else if (b < 1984) {
    const int f = b - 704;
    prep_wt2_body(W1, w1T, 224, 600, 256, 640, (size_t)224 * 600, (size_t)640 * 256,
                  f % 160, f / 160, T);
  } else if (b < 5184) {
    const int f = b - 1984;
    prep_wt2_body(W2, w2T, 600, 600, 640, 640, (size_t)600 * 600, (size_t)640 * 640,
                  f % 400, f / 400, T);
  } else if (b < 6464) {
    const int f = b - 5184;
    prep_wt2_body(W3, w3T, 600, 224, 640, 256, (size_t)600 * 224, (size_t)256 * 640,
                  f % 160, f / 160, T);
  } else if (b < 8480) {
    prep_wt2_body(Wf, wfT, 224, 8000, 256, 8064, 0, 0, b - 6464, 0, T);
  } else {
    // lnconst: per-layer Sw, Sw2, Sb, Sb2, Swb
    const int f = b - 8480;             // 512 blocks: g in [0,64), ll in [0,8)
    const int g = f & 63, ll = f >> 6;
    const float* wv = lnw + (size_t)ll * SD + g * 3584;
    const float* bv = lnb + (size_t)ll * SD + g * 3584;
    float s[5] = {0.f, 0.f, 0.f, 0.f, 0.f};
    for (int c = threadIdx.x * 4; c < 3584; c += 1024) {
      float4 w4 = *(const float4*)(wv + c);
      float4 b4 = *(const float4*)(bv + c);
      const float* wf2 = (const float*)&w4;
      const float* bf2 = (const float*)&b4;
#pragma unroll
      for (int e = 0; e < 4; ++e) {
        const float ww = wf2[e], bb = bf2[e];
        s[0] += ww; s[1] += ww * ww; s[2] += bb; s[3] += bb * bb; s[4] += ww * bb;
      }
    }
#pragma unroll
    for (int o2 = 32; o2 > 0; o2 >>= 1)
#pragma unroll
      for (int j = 0; j < 5; ++j) s[j] += __shfl_down(s[j], o2);
    float* red = T;   // reuse
    if ((threadIdx.x & 63) == 0)
#pragma unroll
      for (int j = 0; j < 5; ++j) red[(threadIdx.x >> 6) * 5 + j] = s[j];
    __syncthreads();
    if (threadIdx.x < 5) {
      const float tot = red[threadIdx.x] + red[5 + threadIdx.x] +
                        red[10 + threadIdx.x] + red[15 + threadIdx.x];
      atomicAdd(&cst[ll * 5 + threadIdx.x], tot);
    }
  }
}

// Coalesced-read qkv weight repack (dest pre-zeroed so pads stay 0).
__global__ void prep_wqkv(const float* __restrict__ Wq, const float* __restrict__ Wk,
                          const float* __restrict__ Wv, const float* __restrict__ bq,
                          const float* __restrict__ bk, const float* __restrict__ bv,
                          unsigned short* __restrict__ O, float* __restrict__ bcat)
{
  const int idx = blockIdx.x * 256 + threadIdx.x;
  if (idx < LLl * 8 * 224 * 28) {
    const int kk = idx % 28;
    const int d  = (idx / 28) % 224;
    const int h  = (idx / (28 * 224)) % 8;
    const int ll = idx / (28 * 224 * 8);
    const int col = h * 28 + kk;
    const size_t base = (size_t)ll * (704 * 256);
    O[base + (size_t)col * 256 + d]         = f2b(Wq[idx]);
    O[base + (size_t)(224 + col) * 256 + d] = f2b(Wk[idx]);
    O[base + (size_t)(448 + col) * 256 + d] = f2b(Wv[idx]);
  }
  if (idx < LLl * 8 * 28) {
    const int kk = idx % 28;
    const int h  = (idx / 28) % 8;
    const int ll = idx / (28 * 8);
    const int col = h * 28 + kk;
    bcat[ll * 672 + col]       = bq[idx];
    bcat[ll * 672 + 224 + col] = bk[idx];
    bcat[ll * 672 + 448 + col] = bv[idx];
  }
}

// x -> bf16; block 0 zeros the stats/cst region (424 floats, STRIDED — the
// region exceeds blockDim; a plain guard left atomic accumulators dirty
// across graph replays: round-10 failure).
__global__ void prep_x(const float* __restrict__ x, unsigned short* __restrict__ xb,
                       float* __restrict__ st)
{
  if (blockIdx.x == 0) {
    for (int i = threadIdx.x; i < 424; i += 256) st[i] = 0.f;
  }
  const size_t i = ((size_t)blockIdx.x * 256 + threadIdx.x) * 4;
  float4 v = *(const float4*)(x + i);
  ushort4 o;
  o.x = f2b(v.x); o.y = f2b(v.y); o.z = f2b(v.z); o.w = f2b(v.w);
  *(ushort4*)(xb + i) = o;
}

// ---------------------------------------------------------------------------
// MFMA flash attention, defer-max rescale (identity-skip, bit-exact).
// ---------------------------------------------------------------------------
__global__ __launch_bounds__(256) void attn_mfma(const unsigned short* __restrict__ qkv,
                                                 unsigned short* __restrict__ o)
{
  const int bh = blockIdx.x;
  const int qt = (int)gridDim.y - 1 - (int)blockIdx.y;
  const int b = bh >> 3, h = bh & 7;
  const int tid = threadIdx.x;
  const int w = tid >> 6, l = tid & 63;
  const int cl = l & 15, g = l >> 4;
  const int qbase = qt * 64 + w * 16;
  const float scale = 0.1889822365046136f;  // 1/sqrt(28)

  __shared__ unsigned short Ks[32 * 40];
  __shared__ unsigned short Vt[32 * 40];
  __shared__ unsigned short Ps[4][16 * 40];

  short8 aq;
  {
    const unsigned short* qp = qkv + ((size_t)(b * SS + qbase + cl)) * 704 + h * 28;
#pragma unroll
    for (int e = 0; e < 8; ++e) {
      const int d = g * 8 + e;
      ((unsigned short*)&aq)[e] = (d < 28) ? qp[d] : (unsigned short)0;
    }
  }

  f32x4 o0 = {0.f, 0.f, 0.f, 0.f}, o1 = {0.f, 0.f, 0.f, 0.f};
  float m[4] = {-INFINITY, -INFINITY, -INFINITY, -INFINITY};
  float lsum[4] = {0.f, 0.f, 0.f, 0.f};

  const int ntiles = qt * 2 + 2;
  const int ntw = ((qbase + 15) >> 5) + 1;

  const int sr = tid >> 3, sc4 = (tid & 7) << 2;
  const bool sact = (sc4 < 28);
  ushort4 ku = make_ushort4(0, 0, 0, 0), vu = make_ushort4(0, 0, 0, 0);
  if (sact) {
    const unsigned short* kp = qkv + ((size_t)(b * SS + sr)) * 704 + 224 + h * 28 + sc4;
    ku = *(const ushort4*)kp;
    vu = *(const ushort4*)(kp + 224);
  }

  for (int tile = 0; tile < ntiles; ++tile) {
    const int t0 = tile * 32;
    __syncthreads();
    *(ushort4*)&Ks[sr * 40 + sc4] = ku;
    Vt[(sc4 + 0) * 40 + sr] = vu.x;
    Vt[(sc4 + 1) * 40 + sr] = vu.y;
    Vt[(sc4 + 2) * 40 + sr] = vu.z;
    Vt[(sc4 + 3) * 40 + sr] = vu.w;
    __syncthreads();
    if (tile + 1 < ntiles && sact) {
      const unsigned short* kp =
          qkv + ((size_t)(b * SS + (tile + 1) * 32 + sr)) * 704 + 224 + h * 28 + sc4;
      ku = *(const ushort4*)kp;
      vu = *(const ushort4*)(kp + 224);
    }
    if (tile >= ntw) continue;

    const short8 bk0 = *(const short8*)&Ks[cl * 40 + g * 8];
    const short8 bk1 = *(const short8*)&Ks[(cl + 16) * 40 + g * 8];
    f32x4 zz = {0.f, 0.f, 0.f, 0.f};
    f32x4 s0 = __builtin_amdgcn_mfma_f32_16x16x32_bf16(aq, bk0, zz, 0, 0, 0);
    f32x4 s1 = __builtin_amdgcn_mfma_f32_16x16x32_bf16(aq, bk1, zz, 0, 0, 0);

    const bool diag = (t0 + 31 > qbase);
#pragma unroll
    for (int jj = 0; jj < 4; ++jj) {
      float v0 = s0[jj] * scale, v1 = s1[jj] * scale;
      if (diag) {
        const int qr = qbase + g * 4 + jj;
        if (t0 + cl > qr)      v0 = -INFINITY;
        if (t0 + 16 + cl > qr) v1 = -INFINITY;
      }
      float rm = fmaxf(v0, v1);
      rm = fmaxf(rm, __shfl_xor(rm, 1));
      rm = fmaxf(rm, __shfl_xor(rm, 2));
      rm = fmaxf(rm, __shfl_xor(rm, 4));
      rm = fmaxf(rm, __shfl_xor(rm, 8));
      if (rm > m[jj]) {           // skip identity rescale (exp(0)=1) otherwise
        const float r2 = __expf(m[jj] - rm);   // first tile: exp(-inf)=0
        m[jj] = rm;
        lsum[jj] *= r2;
        o0[jj] *= r2; o1[jj] *= r2;
      }
      const float e0 = __expf(v0 - m[jj]), e1 = __expf(v1 - m[jj]);
      lsum[jj] += e0 + e1;
      Ps[w][(g * 4 + jj) * 40 + cl]      = f2b(e0);
      Ps[w][(g * 4 + jj) * 40 + cl + 16] = f2b(e1);
    }
    const short8 pa  = *(const short8*)&Ps[w][cl * 40 + g * 8];
    const short8 bv0 = *(const short8*)&Vt[cl * 40 + g * 8];
    const short8 bv1 = *(const short8*)&Vt[(cl + 16) * 40 + g * 8];
    o0 = __builtin_amdgcn_mfma_f32_16x16x32_bf16(pa, bv0, o0, 0, 0, 0);
    o1 = __builtin_amdgcn_mfma_f32_16x16x32_bf16(pa, bv1, o1, 0, 0, 0);
  }

#pragma unroll
  for (int jj = 0; jj < 4; ++jj) {
    float ls = lsum[jj];
    ls += __shfl_xor(ls, 1);
    ls += __shfl_xor(ls, 2);
    ls += __shfl_xor(ls, 4);
    ls += __shfl_xor(ls, 8);
    const float inv = 1.0f / ls;
    const int row = qbase + g * 4 + jj;
    unsigned short* op = o + ((size_t)(b * SS + row)) * 256 + h * 28;
    op[cl] = f2b(o0[jj] * inv);
    if (cl < 12) op[16 + cl] = f2b(o1[jj] * inv);
  }
}

// ---------------------------------------------------------------------------
// Row softmax over V=8000: 512 threads, row register-resident (4 float4 per
// thread covers 8192 >= 8000 slots) — no 32KB LDS row buffer, higher occupancy.
// ---------------------------------------------------------------------------
__global__ __launch_bounds__(512) void softmax_rows(float* __restrict__ logits)
{
  const int row = blockIdx.x;
  float* p = logits + (size_t)row * VV;
  __shared__ float red[8];
  const int tid = threadIdx.x;
  constexpr int NCH = VV / 4;   // 2000 16B chunks

  float4 v[4];
  float mx = -INFINITY;
#pragma unroll
  for (int i = 0; i < 4; ++i) {
    const int ch = tid + i * 512;
    if (ch < NCH) {
      v[i] = *(const float4*)(p + ch * 4);
      mx = fmaxf(fmaxf(fmaxf(mx, v[i].x), fmaxf(v[i].y, v[i].z)), v[i].w);
    }
  }
#pragma unroll
  for (int o2 = 32; o2 > 0; o2 >>= 1) mx = fmaxf(mx, __shfl_down(mx, o2));
  if ((tid & 63) == 0) red[tid >> 6] = mx;
  __syncthreads();
  mx = red[0];
#pragma unroll
  for (int ww = 1; ww < 8; ++ww) mx = fmaxf(mx, red[ww]);
  __syncthreads();

  float s = 0.f;
#pragma unroll
  for (int i = 0; i < 4; ++i) {
    const int ch = tid + i * 512;
    if (ch < NCH) {
      v[i].x = __expf(v[i].x - mx); v[i].y = __expf(v[i].y - mx);
      v[i].z = __expf(v[i].z - mx); v[i].w = __expf(v[i].w - mx);
      s += v[i].x + v[i].y + v[i].z + v[i].w;
    }
  }
#pragma unroll
  for (int o2 = 32; o2 > 0; o2 >>= 1) s += __shfl_down(s, o2);
  if ((tid & 63) == 0) red[tid >> 6] = s;
  __syncthreads();
  s = red[0];
#pragma unroll
  for (int ww = 1; ww < 8; ++ww) s += red[ww];
  const float inv = 1.0f / s;
#pragma unroll
  for (int i = 0; i < 4; ++i) {
    const int ch = tid + i * 512;
    if (ch < NCH) {
      v[i].x *= inv; v[i].y *= inv; v[i].z *= inv; v[i].w *= inv;
      *(float4*)(p + ch * 4) = v[i];
    }
  }
}

// ---------------------------------------------------------------------------
extern "C" void kernel_launch(void* const* d_in, const int* in_sizes, int n_in,
                              void* d_out, int out_size, void* d_ws, size_t ws_size,
                              hipStream_t stream) {
  const float* x   = (const float*)d_in[0];
  const float* Wp  = (const float*)d_in[1];
  const float* bp  = (const float*)d_in[2];
  const float* Wq  = (const float*)d_in[3];
  const float* bq  = (const float*)d_in[4];
  const float* Wk  = (const float*)d_in[5];
  const float* bk  = (const float*)d_in[6];
  const float* Wv  = (const float*)d_in[7];
  const float* bv  = (const float*)d_in[8];
  const float* Wo  = (const float*)d_in[9];
  const float* bo  = (const float*)d_in[10];
  const float* W1  = (const float*)d_in[11];
  const float* b1  = (const float*)d_in[12];
  const float* W2  = (const float*)d_in[13];
  const float* b2  = (const float*)d_in[14];
  const float* W3  = (const float*)d_in[15];
  const float* b3  = (const float*)d_in[16];
  const float* lnw = (const float*)d_in[17];
  const float* lnb = (const float*)d_in[18];
  const float* Wf  = (const float*)d_in[19];
  const float* bf  = (const float*)d_in[20];

  unsigned short* wsb = (unsigned short*)d_ws;
  unsigned short* wpT   = wsb + WP;
  unsigned short* wqkvT = wsb + WQKV;
  unsigned short* woT   = wsb + WO;
  unsigned short* w1T   = wsb + W1T;
  unsigned short* w2T   = wsb + W2T;
  unsigned short* w3T   = wsb + W3T;
  unsigned short* wfT   = wsb + WFT;
  unsigned short* X     = wsb + HB;    // pre-LN layer state
  unsigned short* h2a   = wsb + H2B;   // attn-block output / hF
  unsigned short* obuf  = wsb + OBUF;
  unsigned short* xb    = wsb + BIG;
  unsigned short* qkvb  = wsb + BIG;
  float* bcat  = (float*)((char*)d_ws + FBYTE);
  float* stats = bcat + LLl * 672;      // 16 slots x 24 floats = 384
  float* cstA  = stats + 384;           // 8 layers x 5 floats = 40

  // ---- prep (3 dispatches + memset) ----
  hipMemsetAsync(wqkvT, 0, (size_t)LLl * 704 * 256 * 2, stream);
  prep_x<<<3072, 256, 0, stream>>>(x, xb, stats);   // block 0 zeros stats+cst (424)
  prep_wqkv<<<1568, 256, 0, stream>>>(Wq, Wk, Wv, bq, bk, bv, wqkvT, bcat);
  prep_weights<<<8992, 256, 0, stream>>>(Wp, Wo, W1, W2, W3, Wf, lnw, lnb,
                                         wpT, woT, w1T, w2T, w3T, wfT, cstA);

  // ---- proj + posenc: X = x @ Wp + bp + pe ----
  gemm_mfma<32, 64, GF_BIAS | GF_POSENC><<<dim3(4, 128), 256, 0, stream>>>(
      xb, wpT, bp, nullptr, X, 768, 224, 256,
      nullptr, nullptr, nullptr, nullptr, nullptr, nullptr, nullptr);

  for (int l = 0; l < LLl; ++l) {
    float* stA = stats + (size_t)(2 * l) * 24;
    float* stB = stats + (size_t)(2 * l + 1) * 24;
    const float* stPrev = stats + (size_t)(2 * l - 1) * 24;   // stB_{l-1}, l>=1
    const float* lnwP = lnw + (size_t)(l - 1) * SD;           // layer l-1 params
    const float* lnbP = lnb + (size_t)(l - 1) * SD;
    const float* cstP = cstA + (l - 1) * 5;
    const float* lnwL = lnw + (size_t)l * SD;
    const float* lnbL = lnb + (size_t)l * SD;

    // 1. qkv = LNLN(X) @ Wqkv + bqkv   (layer 0: plain X)
    if (l == 0) {
      gemm_mfma<64, 64, GF_BIAS><<<dim3(11, 64), 256, 0, stream>>>(
          X, wqkvT, bcat, nullptr, qkvb, 256, 672, 704,
          nullptr, nullptr, nullptr, nullptr, nullptr, nullptr, nullptr);
    } else {
      gemm_mfma<64, 64, GF_BIAS | GF_LNA2><<<dim3(11, 64), 256, 0, stream>>>(
          X, wqkvT + (size_t)l * 704 * 256, bcat + l * 672, nullptr, qkvb, 256, 672, 704,
          lnwP, lnbP, stPrev, cstP, nullptr, nullptr, nullptr);
    }
    // 2. attention
    attn_mfma<<<dim3(BB * 8, SS / 64), 256, 0, stream>>>(qkvb, obuf);
    // 3. h2a = obuf @ Wo + bo + LNLN(X); stat6 -> stA
    if (l == 0) {
      gemm_mfma<32, 64, GF_BIAS | GF_RESID | GF_STAT6><<<dim3(4, 128), 256, 0, stream>>>(
          obuf, woT, bo, X, h2a, 256, 224, 256,
          nullptr, nullptr, nullptr, nullptr, lnwL, lnbL, stA);
    } else {
      gemm_mfma<32, 64, GF_BIAS | GF_RESID | GF_LNRES2 | GF_STAT6>
          <<<dim3(4, 128), 256, 0, stream>>>(
          obuf, woT + (size_t)l * 256 * 256, bo + (size_t)l * 224, X, h2a, 256, 224, 256,
          lnwP, lnbP, stPrev, cstP, lnwL, lnbL, stA);
    }
    // 4. fused FFN: X = relu(relu(LN(h2a)@W1)@W2)@W3 + b3 + LN(h2a); stat6 -> stB
    ffn_fused<<<256, 512, 0, stream>>>(
        h2a, w1T + (size_t)l * 640 * 256, w2T + (size_t)l * 640 * 640,
        w3T + (size_t)l * 256 * 640, b1 + (size_t)l * 600, b2 + (size_t)l * 600,
        b3 + (size_t)l * 224, lnwL, lnbL, stA, stB, X);
  }

  // ---- hF = LNLN(X; stB7) materialized once, logits, softmax ----
  ln2mat<<<512, 256, 0, stream>>>(X, lnw + (size_t)7 * SD, lnb + (size_t)7 * SD,
                                  stats + (size_t)15 * 24, cstA + 7 * 5, h2a);
  gemm_mfma<128, 128, GF_BIAS | GF_F32OUT | GF_SWAP><<<dim3(32, 63), 256, 0, stream>>>(
      h2a, wfT, bf, nullptr, (float*)d_out, 256, 8000, 8000,
      nullptr, nullptr, nullptr, nullptr, nullptr, nullptr, nullptr);
  softmax_rows<<<4096, 512, 0, stream>>>((float*)d_out);
}